// Round 1
// baseline (748.222 us; speedup 1.0000x reference)
//
#include <hip/hip_runtime.h>
#include <math.h>

#define D_MODEL 1024
#define N_TOK   8192
#define SEQ_L   1024
#define N_HEAD  16
#define HEAD_D  64
#define FF_DIM  4096

typedef __attribute__((ext_vector_type(8))) short bf16x8;   // 8 bf16 = 4 VGPRs
typedef __attribute__((ext_vector_type(4))) short short4v;
typedef __attribute__((ext_vector_type(2))) int  int2v;
typedef __attribute__((ext_vector_type(4))) float f32x4;

#define MFMA16(a, b, c) __builtin_amdgcn_mfma_f32_16x16x32_bf16((a), (b), (c), 0, 0, 0)

// async global->LDS, 16B per lane; LDS dest = wave-uniform base + lane*16
#define GLD16(gp, lp) __builtin_amdgcn_global_load_lds(                      \
    (const __attribute__((address_space(1))) void*)(gp),                     \
    (__attribute__((address_space(3))) void*)(lp), 16, 0, 0)

#if defined(__has_builtin)
#if __has_builtin(__builtin_amdgcn_exp2f)
#define EXP2F(x) __builtin_amdgcn_exp2f(x)
#else
#define EXP2F(x) exp2f(x)
#endif
#else
#define EXP2F(x) exp2f(x)
#endif

__device__ __forceinline__ short f2bf(float f) {   // fp32 -> bf16 (RNE)
    unsigned u = __float_as_uint(f);
    u += 0x7fffu + ((u >> 16) & 1u);
    return (short)(u >> 16);
}

// pack two fp32 -> two bf16 (round-nearest-up) in one v_perm
__device__ __forceinline__ int pack2bf(float a, float b) {
    unsigned ua = __float_as_uint(a) + 0x8000u;
    unsigned ub = __float_as_uint(b) + 0x8000u;
    return __builtin_amdgcn_perm(ub, ua, 0x07060302u);
}

// ---------------------------------------------------------------------------
// LayerNorm fp32 -> bf16. One block (256 thr) per token.
// ---------------------------------------------------------------------------
__global__ __launch_bounds__(256) void ln_kernel(const float* __restrict__ x,
                                                 const float* __restrict__ g,
                                                 const float* __restrict__ b,
                                                 short* __restrict__ o)
{
    int t = blockIdx.x;
    const float* xr = x + (size_t)t * D_MODEL;
    short* orow = o + (size_t)t * D_MODEL;
    float vals[4];
    float lsum = 0.f, lsq = 0.f;
#pragma unroll
    for (int i = 0; i < 4; i++) {
        float v = xr[threadIdx.x + i * 256];
        vals[i] = v; lsum += v; lsq += v * v;
    }
#pragma unroll
    for (int off = 32; off > 0; off >>= 1) {
        lsum += __shfl_down(lsum, off);
        lsq  += __shfl_down(lsq,  off);
    }
    __shared__ float red[8];
    int wid = threadIdx.x >> 6, lane = threadIdx.x & 63;
    if (lane == 0) { red[wid] = lsum; red[4 + wid] = lsq; }
    __syncthreads();
    if (threadIdx.x == 0) {
        red[0] = red[0] + red[1] + red[2] + red[3];
        red[4] = red[4] + red[5] + red[6] + red[7];
    }
    __syncthreads();
    float mean = red[0] * (1.f / D_MODEL);
    float var  = red[4] * (1.f / D_MODEL) - mean * mean;
    float inv  = rsqrtf(var + 1e-5f);
#pragma unroll
    for (int i = 0; i < 4; i++) {
        int c = threadIdx.x + i * 256;
        orow[c] = f2bf((vals[i] - mean) * inv * g[c] + b[c]);
    }
}

// ---------------------------------------------------------------------------
// Fused prep: six W [K,N] fp32 -> W^T [N,K] bf16 transposes + fp32 mask,
// all in ONE dispatch. Block id ranges select the job; 32x32 tiles.
// ---------------------------------------------------------------------------
__global__ __launch_bounds__(256) void prep_kernel(
    const float* __restrict__ wq, const float* __restrict__ wk,
    const float* __restrict__ wv, const float* __restrict__ wo,
    const float* __restrict__ w1, const float* __restrict__ w2,
    const int*   __restrict__ amask,
    short* __restrict__ wqkvt, short* __restrict__ wot,
    short* __restrict__ w1t,  short* __restrict__ w2t,
    float* __restrict__ fmask)
{
    int id = blockIdx.x;
    if (id >= 12288) {   // mask job: 32 blocks x 256 = 8192 entries
        int i = (id - 12288) * 256 + threadIdx.x;
        fmask[i] = (amask[i] > 0) ? 0.f : -1e30f;
        return;
    }
    const float* src; short* dst; int R, C, tloc, csh;
    if (id < 4096) {
        int wsel = id >> 10; tloc = id & 1023; R = 1024; C = 1024; csh = 5;
        src = (wsel == 0) ? wq : (wsel == 1) ? wk : (wsel == 2) ? wv : wo;
        dst = (wsel == 3) ? wot : (wqkvt + (size_t)wsel * 1024 * 1024);
    } else if (id < 8192) {
        tloc = id - 4096; R = 1024; C = 4096; csh = 7; src = w1; dst = w1t;
    } else {
        tloc = id - 8192; R = 4096; C = 1024; csh = 5; src = w2; dst = w2t;
    }
    int ty = tloc >> csh, tx = tloc & ((1 << csh) - 1);
    int r0 = ty * 32, c0 = tx * 32;
    __shared__ float t[32][33];
    int tid = threadIdx.x;
#pragma unroll
    for (int i = 0; i < 4; i++) {
        int idx = i * 256 + tid;
        int r = idx >> 5, c = idx & 31;
        t[r][c] = src[(size_t)(r0 + r) * C + c0 + c];
    }
    __syncthreads();
#pragma unroll
    for (int i = 0; i < 4; i++) {
        int idx = i * 256 + tid;
        int rr = idx >> 5, cc = idx & 31;
        dst[(size_t)(c0 + rr) * R + r0 + cc] = f2bf(t[cc][rr]);
    }
}

// ---------------------------------------------------------------------------
// Legacy 128x128 GEMM (dbuf) — kept for the small O-projection (N=1024).
// ---------------------------------------------------------------------------
template<int DBUF>
__global__ __launch_bounds__(256) void gemm_bf16(
    const short* __restrict__ A, int lda,
    const short* __restrict__ Bt, int ldb,
    const float* __restrict__ bias,
    const float* __restrict__ bias2,
    const float* __restrict__ bias3,
    const float* __restrict__ resid,
    float* __restrict__ Cf, short* __restrict__ Cb, short* __restrict__ Cvt,
    int ldc, int K, int act, int qkv, int gx)
{
    __shared__ __align__(16) short sA[(1 + DBUF) * 8192];   // swizzled
    __shared__ __align__(16) short sB[(1 + DBUF) * 8192];
    const int tid = threadIdx.x;
    const int lane = tid & 63, wave = tid >> 6;
    const int quad = lane >> 4, l15 = lane & 15;

    const int id = blockIdx.x;
    const int xcd = id & 7, j = id >> 3;
    const int bx = j % gx, by = xcd + 8 * (j / gx);
    const int bm = by * 128, bn = bx * 128;
    const int wm = (wave >> 1) * 64, wn = (wave & 1) * 64;

    const int lr = lane >> 3;            // 0..7 row within an 8-row call
    const int lc = (lane & 7) ^ lr;      // chunk ^ (row&7)
    const int sw = l15 & 7;              // read-side swizzle key

    const short* Ab = A  + (size_t)(bm + wave * 32 + lr) * lda + lc * 8;
    const short* Bb = Bt + (size_t)(bn + wave * 32 + lr) * ldb + lc * 8;

    f32x4 acc[4][4];
#pragma unroll
    for (int i = 0; i < 4; i++)
#pragma unroll
        for (int jj = 0; jj < 4; jj++) acc[i][jj] = (f32x4){0.f, 0.f, 0.f, 0.f};

    const int nk = K >> 6;

    if (DBUF) {
#pragma unroll
        for (int c = 0; c < 4; c++) {
            int cid = wave * 4 + c;
            GLD16(Ab + (size_t)(c * 8) * lda, &sA[cid * 512]);
            GLD16(Bb + (size_t)(c * 8) * ldb, &sB[cid * 512]);
        }
    }

    for (int ki = 0; ki < nk; ki++) {
        __syncthreads();
        if (DBUF) {
            if (ki + 1 < nk) {
                int k0 = (ki + 1) << 6, nb = (ki + 1) & 1;
#pragma unroll
                for (int c = 0; c < 4; c++) {
                    int cid = wave * 4 + c;
                    GLD16(Ab + (size_t)(c * 8) * lda + k0, &sA[nb * 8192 + cid * 512]);
                    GLD16(Bb + (size_t)(c * 8) * ldb + k0, &sB[nb * 8192 + cid * 512]);
                }
            }
        } else {
            int k0 = ki << 6;
#pragma unroll
            for (int c = 0; c < 4; c++) {
                int cid = wave * 4 + c;
                GLD16(Ab + (size_t)(c * 8) * lda + k0, &sA[cid * 512]);
                GLD16(Bb + (size_t)(c * 8) * ldb + k0, &sB[cid * 512]);
            }
            __syncthreads();
        }
        const short* cA = &sA[DBUF ? (ki & 1) * 8192 : 0];
        const short* cB = &sB[DBUF ? (ki & 1) * 8192 : 0];
#pragma unroll
        for (int ko = 0; ko < 2; ko++) {
            bf16x8 af[4], bfr[4];
#pragma unroll
            for (int mt = 0; mt < 4; mt++) {
                int row = wm + mt * 16 + l15;
                af[mt] = *(const bf16x8*)&cA[(row * 8 + ((ko * 4 + quad) ^ sw)) * 8];
            }
#pragma unroll
            for (int nt = 0; nt < 4; nt++) {
                int row = wn + nt * 16 + l15;
                bfr[nt] = *(const bf16x8*)&cB[(row * 8 + ((ko * 4 + quad) ^ sw)) * 8];
            }
#pragma unroll
            for (int mt = 0; mt < 4; mt++)
#pragma unroll
                for (int nt = 0; nt < 4; nt++)
                    acc[mt][nt] = MFMA16(af[mt], bfr[nt], acc[mt][nt]);
        }
    }

#pragma unroll
    for (int mt = 0; mt < 4; mt++)
#pragma unroll
        for (int nt = 0; nt < 4; nt++) {
            int row0 = bm + wm + mt * 16 + quad * 4;
            int col  = bn + wn + nt * 16 + l15;
            if (qkv) {
                int seg = col >> 10, cloc = col & 1023;
                const float* bp = (seg == 0) ? bias : (seg == 1) ? bias2 : bias3;
                float bval = bp[cloc];
                if (seg == 2) {
                    int bb = row0 >> 10, l0 = row0 & 1023;
                    size_t page = (size_t)(bb * N_HEAD + (cloc >> 6)) * HEAD_D + (cloc & 63);
                    short4v pk = { f2bf(acc[mt][nt][0] + bval), f2bf(acc[mt][nt][1] + bval),
                                   f2bf(acc[mt][nt][2] + bval), f2bf(acc[mt][nt][3] + bval) };
                    *(short4v*)&Cvt[page * SEQ_L + l0] = pk;
                } else {
                    short* dst = Cb + (size_t)seg * ((size_t)N_TOK * D_MODEL);
#pragma unroll
                    for (int r = 0; r < 4; r++)
                        dst[(size_t)(row0 + r) * D_MODEL + cloc] = f2bf(acc[mt][nt][r] + bval);
                }
            } else {
#pragma unroll
                for (int r = 0; r < 4; r++) {
                    int row = row0 + r;
                    float v = acc[mt][nt][r] + bias[col];
                    if (act) v = v / (1.f + __expf(-1.702f * v));   // quick_gelu
                    if (resid) v += resid[(size_t)row * ldc + col];
                    if (Cb) Cb[(size_t)row * ldc + col] = f2bf(v);
                    else    Cf[(size_t)row * ldc + col] = f2bf(v), Cf[(size_t)row * ldc + col] = v;
                }
            }
        }
}

// ---------------------------------------------------------------------------
// 256x256 (NREP=4) / 256x128 (NREP=2) 8-phase GEMM, BK=64, 512 thr = 8 waves
// (2M x 4N). T2 XOR-swizzle (pre-swizzled global source, linear LDS dest),
// T3+T4 counted vmcnt (never 0 in loop), T5 setprio around MFMA clusters.
//
// Stage schedule (one half-tile per phase; tile t in buf0, t+1 in buf1):
//   ph1:(t+1).A1   ph2:(t+2).B0  ph3:(t+2).B1  ph4:(t+2).A0 [vmcnt]
//   ph5:(t+2).A1   ph6:(t+3).B0  ph7:(t+3).B1  ph8:(t+3).A0 [vmcnt]
// Read schedule: each wave reads ALL its B frags + A m0-3 in ph1/ph5,
// A m4-7 in ph3/ph7 -> every region's last read-phase < its re-stage phase.
// vmcnt leaves exactly 3 half-tiles in flight: 2*LB+LA loads
// (NREP=4: 6, NREP=2: 4).
// ---------------------------------------------------------------------------
#define BAR() __builtin_amdgcn_s_barrier()
#define WAIT_LGKM0() do { asm volatile("s_waitcnt lgkmcnt(0)");               \
                          __builtin_amdgcn_sched_barrier(0); } while (0)

#define STA(buf, h, tt) do {                                                  \
    const short* s_ = Asrc + (size_t)((h) * 128) * lda + (size_t)(tt) * 64;   \
    GLD16(s_,                    &sAs[(buf)*16384 + (h)*8192        + wave*512]); \
    GLD16(s_ + (size_t)64 * lda, &sAs[(buf)*16384 + (h)*8192 + 4096 + wave*512]); \
} while (0)

#define STB(buf, h, tt) do {                                                  \
    if constexpr (NREP == 4) {                                                \
        const short* s_ = Bsrc + (size_t)((h) * 128) * ldb + (size_t)(tt) * 64; \
        GLD16(s_,                    &sBs[(buf)*16384 + (h)*8192        + wave*512]); \
        GLD16(s_ + (size_t)64 * ldb, &sBs[(buf)*16384 + (h)*8192 + 4096 + wave*512]); \
    } else {                                                                  \
        const short* s_ = Bsrc + (size_t)((h) * 64) * ldb + (size_t)(tt) * 64; \
        GLD16(s_, &sBs[(buf)*8192 + (h)*4096 + wave*512]);                    \
    }                                                                         \
} while (0)

#define VMCNT() do {                                                          \
    if constexpr (NREP == 4) asm volatile("s_waitcnt vmcnt(6)");              \
    else                     asm volatile("s_waitcnt vmcnt(4)");              \
} while (0)

#define LDA_F(buf, mt, ko) (*(const bf16x8*)&sAs[(buf)*16384 +                \
    (((wm + (mt)*16 + l15) << 3) + (((ko)*4 + quad) ^ sw)) * 8])
#define LDB_F(buf, nt, ko) (*(const bf16x8*)&sBs[(buf)*(NREP == 4 ? 16384 : 8192) + \
    (((wn + (nt)*16 + l15) << 3) + (((ko)*4 + quad) ^ sw)) * 8])

#define PH_READ_B(buf)                                                        \
    _Pragma("unroll")                                                         \
    for (int nt = 0; nt < NREP; nt++) {                                       \
        bfr[nt][0] = LDB_F(buf, nt, 0);                                       \
        bfr[nt][1] = LDB_F(buf, nt, 1);                                       \
    }
#define PH_READ_A(buf, mh)                                                    \
    _Pragma("unroll")                                                         \
    for (int mt = 0; mt < 4; mt++) {                                          \
        afr[mt][0] = LDA_F(buf, (mh)*4 + mt, 0);                              \
        afr[mt][1] = LDA_F(buf, (mh)*4 + mt, 1);                              \
    }
#define PH_MFMA(mh, nh)                                                       \
    __builtin_amdgcn_s_setprio(1);                                            \
    _Pragma("unroll")                                                         \
    for (int mt = 0; mt < 4; mt++)                                            \
        _Pragma("unroll")                                                     \
        for (int nt = 0; nt < NREP / 2; nt++) {                               \
            acc[(mh)*4 + mt][(nh)*(NREP/2) + nt] =                            \
                MFMA16(afr[mt][0], bfr[(nh)*(NREP/2) + nt][0],                \
                       acc[(mh)*4 + mt][(nh)*(NREP/2) + nt]);                 \
            acc[(mh)*4 + mt][(nh)*(NREP/2) + nt] =                            \
                MFMA16(afr[mt][1], bfr[(nh)*(NREP/2) + nt][1],                \
                       acc[(mh)*4 + mt][(nh)*(NREP/2) + nt]);                 \
        }                                                                     \
    __builtin_amdgcn_s_setprio(0);

template<int NREP>   // NREP=4 -> BN=256, NREP=2 -> BN=128
__global__ __launch_bounds__(512, 2) void gemm256(
    const short* __restrict__ A, int lda,
    const short* __restrict__ Bt, int ldb,
    const float* __restrict__ bias,
    const float* __restrict__ bias2,
    const float* __restrict__ bias3,
    const float* __restrict__ resid,
    float* __restrict__ Cf, short* __restrict__ Cb, short* __restrict__ Cvt,
    int ldc, int K, int act, int qkv, int gx)
{
    constexpr int BN = NREP * 64;
    __shared__ __align__(16) short sAs[2 * 256 * 64];   // 64 KB, dbuf
    __shared__ __align__(16) short sBs[2 * BN  * 64];   // 64/32 KB, dbuf

    const int tid  = threadIdx.x;
    const int wave = tid >> 6, lane = tid & 63;
    const int quad = lane >> 4, l15 = lane & 15;
    const int wm = (wave >> 2) * 128;            // warp_m * 128
    const int wn = (wave & 3) * (NREP * 16);     // warp_n * per-wave N
    const int sw = l15 & 7;

    // XCD row-panel swizzle
    const int id = blockIdx.x;
    const int xcd = id & 7, j = id >> 3;
    const int bx = j % gx, by = xcd + 8 * (j / gx);
    const int bm = by * 256, bn = bx * BN;

    // staging decomposition: thread tid covers (row = tid>>3, chunk = tid&7)
    // of a 64-row call; source chunk pre-swizzled so linear LDS == swizzled.
    const int r_in = tid >> 3;
    const int csrc = (tid & 7) ^ (r_in & 7);
    const short* Asrc = A  + (size_t)(bm + r_in) * lda + csrc * 8;
    const short* Bsrc = Bt + (size_t)(bn + r_in) * ldb + csrc * 8;

    f32x4 acc[8][NREP];
#pragma unroll
    for (int i = 0; i < 8; i++)
#pragma unroll
        for (int jj = 0; jj < NREP; jj++) acc[i][jj] = (f32x4){0.f, 0.f, 0.f, 0.f};

    const int nk = K >> 6;

    // prologue: tile0 (B0,B1,A0,A1) + tile1 (B0,B1,A0); wait tile0 landed
    STB(0, 0, 0); STB(0, 1, 0);
    STA(0, 0, 0); STA(0, 1, 0);
    STB(1, 0, 1); STB(1, 1, 1);
    STA(1, 0, 1);
    VMCNT();
    BAR();

    bf16x8 afr[4][2], bfr[NREP][2];

    for (int it = 0; it < nk; it += 2) {
        int t2 = it + 2; if (t2 >= nk) t2 -= nk;   // wrapped dummy stages keep
        int t3 = it + 3; if (t3 >= nk) t3 -= nk;   // vmcnt counts uniform

        // -------- PH1: tile t (buf0), m0-3 x nlo --------
        PH_READ_B(0); PH_READ_A(0, 0);
        STA(1, 1, it + 1);
        BAR(); WAIT_LGKM0();
        PH_MFMA(0, 0);
        BAR();
        // -------- PH2: m0-3 x nhi --------
        STB(0, 0, t2);
        BAR();
        PH_MFMA(0, 1);
        BAR();
        // -------- PH3: m4-7 x nhi --------
        PH_READ_A(0, 1);
        STB(0, 1, t2);
        BAR(); WAIT_LGKM0();
        PH_MFMA(1, 1);
        BAR();
        // -------- PH4: m4-7 x nlo, counted vmcnt --------
        STA(0, 0, t2);
        BAR();
        PH_MFMA(1, 0);
        VMCNT();
        BAR();
        // -------- PH5: tile t+1 (buf1), m0-3 x nlo --------
        PH_READ_B(1); PH_READ_A(1, 0);
        STA(0, 1, t2);
        BAR(); WAIT_LGKM0();
        PH_MFMA(0, 0);
        BAR();
        // -------- PH6: m0-3 x nhi --------
        STB(1, 0, t3);
        BAR();
        PH_MFMA(0, 1);
        BAR();
        // -------- PH7: m4-7 x nhi --------
        PH_READ_A(1, 1);
        STB(1, 1, t3);
        BAR(); WAIT_LGKM0();
        PH_MFMA(1, 1);
        BAR();
        // -------- PH8: m4-7 x nlo, counted vmcnt --------
        STA(1, 0, t3);
        BAR();
        PH_MFMA(1, 0);
        VMCNT();
        BAR();
    }

    // epilogue (same C/D mapping as legacy kernel: col=lane&15, row=quad*4+r)
#pragma unroll
    for (int mt = 0; mt < 8; mt++)
#pragma unroll
        for (int nt = 0; nt < NREP; nt++) {
            int row0 = bm + wm + mt * 16 + quad * 4;
            int col  = bn + wn + nt * 16 + l15;
            if (qkv) {
                int seg = col >> 10, cloc = col & 1023;
                const float* bp = (seg == 0) ? bias : (seg == 1) ? bias2 : bias3;
                float bval = bp[cloc];
                if (seg == 2) {
                    int bb = row0 >> 10, l0 = row0 & 1023;
                    size_t page = (size_t)(bb * N_HEAD + (cloc >> 6)) * HEAD_D + (cloc & 63);
                    short4v pk = { f2bf(acc[mt][nt][0] + bval), f2bf(acc[mt][nt][1] + bval),
                                   f2bf(acc[mt][nt][2] + bval), f2bf(acc[mt][nt][3] + bval) };
                    *(short4v*)&Cvt[page * SEQ_L + l0] = pk;
                } else {
                    short* dst = Cb + (size_t)seg * ((size_t)N_TOK * D_MODEL);
#pragma unroll
                    for (int r = 0; r < 4; r++)
                        dst[(size_t)(row0 + r) * D_MODEL + cloc] = f2bf(acc[mt][nt][r] + bval);
                }
            } else {
#pragma unroll
                for (int r = 0; r < 4; r++) {
                    int row = row0 + r;
                    float v = acc[mt][nt][r] + bias[col];
                    if (act) v = v / (1.f + __expf(-1.702f * v));   // quick_gelu
                    if (resid) v += resid[(size_t)row * ldc + col];
                    if (Cb) Cb[(size_t)row * ldc + col] = f2bf(v);
                    else    Cf[(size_t)row * ldc + col] = v;
                }
            }
        }
}

// ---------------------------------------------------------------------------
// Flash attention, 128 q-rows/block (unchanged from prior session).
// ---------------------------------------------------------------------------
__global__ __launch_bounds__(256) void attn_kernel(
    const short* __restrict__ Q, const short* __restrict__ Kb,
    const short* __restrict__ Vt, const float* __restrict__ fmask,
    short* __restrict__ O)
{
    __shared__ __align__(16) short sK[8192];        // 16KB: slot=kc*128+key
    __shared__ __align__(16) short sV[8192];        // 16KB: slot=kc2*64+d
    __shared__ __align__(16) short sP[4][32 * 136]; // per-wave [32 q][136]
    __shared__ __align__(16) float sAl[4][2][20];

    const int g = blockIdx.x;
    const int xcd = g & 7, slot = g >> 3;
    const int qt = slot & 7, bhl = slot >> 3;
    const int bh = xcd * 16 + bhl;
    const int b = bh >> 4, h = bh & 15;

    const int tid = threadIdx.x;
    const int wave = tid >> 6, lane = tid & 63;
    const int quad = lane >> 4, l15 = lane & 15;

    const int qbase = b * SEQ_L + qt * 128;
    bf16x8 qf[2][2];
#pragma unroll
    for (int qh = 0; qh < 2; qh++) {
        const short* qp = Q + (size_t)(qbase + wave * 32 + qh * 16 + l15) * D_MODEL
                        + h * HEAD_D + quad * 8;
        qf[qh][0] = *(const bf16x8*)qp;
        qf[qh][1] = *(const bf16x8*)(qp + 32);
    }

    const short* Kbh = Kb + (size_t)b * SEQ_L * D_MODEL + h * HEAD_D;
    const short* Vbh = Vt + (size_t)(b * N_HEAD + h) * HEAD_D * SEQ_L;
    const float* mk  = fmask + b * SEQ_L;

    f32x4 o4[2][4];
#pragma unroll
    for (int qh = 0; qh < 2; qh++)
#pragma unroll
        for (int nt = 0; nt < 4; nt++) o4[qh][nt] = (f32x4){0.f, 0.f, 0.f, 0.f};
    float mrow[2] = {-1e30f, -1e30f}, lrow[2] = {0.f, 0.f};
    short* pslab = &sP[wave][0];         // per-wave private [32 q][136]
    const float CSC = 0.125f * 1.4426950408889634f;   // scale * log2(e)

    for (int kt = 0; kt < SEQ_L / 128; kt++) {
        __syncthreads();   // previous iter's frag reads done
#pragma unroll
        for (int j = 0; j < 4; j++) {
            int cid = wave * 4 + j;
            int kc = cid >> 1, key0 = (cid & 1) << 6;
            GLD16(Kbh + (size_t)(kt * 128 + key0 + lane) * D_MODEL + kc * 8,
                  &sK[cid * 512]);
            GLD16(Vbh + (size_t)lane * SEQ_L + kt * 128 + cid * 8,
                  &sV[cid * 512]);
        }
        __syncthreads();   // staging complete (vmcnt drained by barrier)

        f32x4 mkv[8];
#pragma unroll
        for (int sub = 0; sub < 8; sub++)
            mkv[sub] = *(const f32x4*)&mk[kt * 128 + sub * 16 + quad * 4];

        f32x4 s[8][2];
#pragma unroll
        for (int sub = 0; sub < 8; sub++) {
            bf16x8 kf0 = *(const bf16x8*)&sK[(quad * 128 + sub * 16 + l15) * 8];
            bf16x8 kf1 = *(const bf16x8*)&sK[((quad + 4) * 128 + sub * 16 + l15) * 8];
#pragma unroll
            for (int qh = 0; qh < 2; qh++) {
                s[sub][qh] = (f32x4){0.f, 0.f, 0.f, 0.f};
                s[sub][qh] = MFMA16(kf0, qf[qh][0], s[sub][qh]);
                s[sub][qh] = MFMA16(kf1, qf[qh][1], s[sub][qh]);
            }
        }
        float alpha[2];
#pragma unroll
        for (int qh = 0; qh < 2; qh++) {
#pragma unroll
            for (int sub = 0; sub < 8; sub++)
#pragma unroll
                for (int r = 0; r < 4; r++)
                    s[sub][qh][r] = s[sub][qh][r] * CSC + mkv[sub][r];
            f32x4 mx4 = s[0][qh];
#pragma unroll
            for (int sub = 1; sub < 8; sub++)
#pragma unroll
                for (int r = 0; r < 4; r++) mx4[r] = fmaxf(mx4[r], s[sub][qh][r]);
            float pmax = fmaxf(fmaxf(mx4[0], mx4[1]), fmaxf(mx4[2], mx4[3]));
            pmax = fmaxf(pmax, __shfl_xor(pmax, 16));
            pmax = fmaxf(pmax, __shfl_xor(pmax, 32));
            float mnew = fmaxf(mrow[qh], pmax);
            alpha[qh] = EXP2F(mrow[qh] - mnew);
            mrow[qh] = mnew;
            if (quad == 0) sAl[wave][qh][l15] = alpha[qh];

            float ls = 0.f;
#pragma unroll
            for (int sub = 0; sub < 8; sub++) {
                float p0 = EXP2F(s[sub][qh][0] - mnew);
                float p1 = EXP2F(s[sub][qh][1] - mnew);
                float p2 = EXP2F(s[sub][qh][2] - mnew);
                float p3 = EXP2F(s[sub][qh][3] - mnew);
                ls += (p0 + p1) + (p2 + p3);
                int2v pk = { pack2bf(p0, p1), pack2bf(p2, p3) };
                *(int2v*)&pslab[(qh * 16 + l15) * 136 + sub * 16 + quad * 4] = pk;
            }
            ls += __shfl_xor(ls, 16);
            ls += __shfl_xor(ls, 32);
            lrow[qh] = lrow[qh] * alpha[qh] + ls;
        }

#pragma unroll
        for (int qh = 0; qh < 2; qh++) {
            f32x4 av = *(const f32x4*)&sAl[wave][qh][quad * 4];
#pragma unroll
            for (int nt = 0; nt < 4; nt++)
#pragma unroll
                for (int r = 0; r < 4; r++) o4[qh][nt][r] *= av[r];
        }

        bf16x8 pf[2][4];
#pragma unroll
        for (int qh = 0; qh < 2; qh++)
#pragma unroll
            for (int c = 0; c < 4; c++)
                pf[qh][c] = *(const bf16x8*)&pslab[(qh * 16 + l15) * 136 + c * 32 + quad * 8];
#pragma unroll
        for (int nt = 0; nt < 4; nt++)
#pragma unroll
            for (int c = 0; c < 4; c++) {
                bf16x8 vfr = *(const bf16x8*)&sV[((c * 4 + quad) * 64 + nt * 16 + l15) * 8];
                o4[0][nt] = MFMA16(pf[0][c], vfr, o4[0][nt]);
                o4[1][nt] = MFMA16(pf[1][c], vfr, o4[1][nt]);
            }
    }
    if (quad == 0) {
        sAl[wave][0][l15] = 1.f / lrow[0];
        sAl[wave][1][l15] = 1.f / lrow[1];
    }
    __syncthreads();
#pragma unroll
    for (int qh = 0; qh < 2; qh++) {
        f32x4 iv = *(const f32x4*)&sAl[wave][qh][quad * 4];
#pragma unroll
        for (int nt = 0; nt < 4; nt++)
#pragma unroll
            for (int r = 0; r < 4; r++)
                O[(size_t)(qbase + wave * 32 + qh * 16 + quad * 4 + r) * D_MODEL
                  + h * HEAD_D + nt * 16 + l15] = f2bf(o4[qh][nt][r] * iv[r]);
    }
}

// ---------------------------------------------------------------------------
// Launch
// ---------------------------------------------------------------------------
extern "C" void kernel_launch(void* const* d_in, const int* in_sizes, int n_in,
                              void* d_out, int out_size, void* d_ws, size_t ws_size,
                              hipStream_t stream)
{
    const float* x     = (const float*)d_in[0];
    const int*   amask = (const int*)  d_in[1];
    const float* wq    = (const float*)d_in[2];
    const float* bq    = (const float*)d_in[3];
    const float* wk    = (const float*)d_in[4];
    const float* bk    = (const float*)d_in[5];
    const float* wv    = (const float*)d_in[6];
    const float* bv    = (const float*)d_in[7];
    const float* wo    = (const float*)d_in[8];
    const float* bo    = (const float*)d_in[9];
    const float* ln1s  = (const float*)d_in[10];
    const float* ln1b  = (const float*)d_in[11];
    const float* ln2s  = (const float*)d_in[12];
    const float* ln2b  = (const float*)d_in[13];
    const float* w1    = (const float*)d_in[14];
    const float* b1    = (const float*)d_in[15];
    const float* w2    = (const float*)d_in[16];
    const float* b2    = (const float*)d_in[17];
    float* out = (float*)d_out;

    char* w = (char*)d_ws;
    short* wqkvt = (short*)(w + (size_t)0);          // [3072][1024] bf16, 6MB
    short* wot   = (short*)(w + ((size_t)6  << 20));
    short* w1t   = (short*)(w + ((size_t)8  << 20));
    short* w2t   = (short*)(w + ((size_t)16 << 20));
    short* hb    = (short*)(w + ((size_t)24 << 20)); // LN1 out, later LN2 out
    short* qb    = (short*)(w + ((size_t)40 << 20)); // qb,kbf contiguous:
    short* kbf   = (short*)(w + ((size_t)56 << 20)); //   16MB stride for qkv mode
    short* attnb = (short*)(w + ((size_t)72 << 20));
    short* vtb   = (short*)(w + ((size_t)88 << 20));
    short* ffb   = qb;   // q/k/vt dead by MLP1 (64 MB span 40..104)
    float* fmaskb = (float*)d_out;

    dim3 blk(256), blk512(512);

    prep_kernel<<<dim3(12320), blk, 0, stream>>>(wq, wk, wv, wo, w1, w2, amask,
                                                 wqkvt, wot, w1t, w2t, fmaskb);

    // 1) h = LN1(x) -> bf16
    ln_kernel<<<N_TOK, blk, 0, stream>>>(x, ln1s, ln1b, hb);

    // 2) fused QKV GEMM: 256^2 8-phase, grid 32x12 = 384
    gemm256<4><<<dim3(384), blk512, 0, stream>>>(
        hb, 1024, wqkvt, 1024, bq, bk, bv, nullptr,
        nullptr, qb, vtb, 1024, 1024, 0, 1, 12);

    // 3) flash attention -> attnb (bf16)
    attn_kernel<<<dim3(1024), blk, 0, stream>>>(qb, kbf, vtb, fmaskb, attnb);

    // 4) out = x + attn @ wo + bo  (small N: keep proven dbuf-128^2 kernel)
    gemm_bf16<1><<<dim3(8 * 64), blk, 0, stream>>>(
        attnb, 1024, wot, 1024, bo, nullptr, nullptr, x,
        out, nullptr, nullptr, 1024, 1024, 0, 0, 8);

    // 5) h = LN2(out) -> bf16
    ln_kernel<<<N_TOK, blk, 0, stream>>>(out, ln2s, ln2b, hb);

    // 6) MLP1: 256^2 8-phase, grid 32x16 = 512; MLP2: 256x128, grid 32x8 = 256
    gemm256<4><<<dim3(512), blk512, 0, stream>>>(
        hb, 1024, w1t, 1024, b1, nullptr, nullptr, nullptr,
        nullptr, ffb, nullptr, 4096, 1024, 1, 0, 16);
    gemm256<2><<<dim3(256), blk512, 0, stream>>>(
        ffb, 4096, w2t, 4096, b2, nullptr, nullptr, out,
        out, nullptr, nullptr, 1024, 4096, 0, 0, 8);
}

// Round 2
// 612.261 us; speedup vs baseline: 1.2221x; 1.2221x over previous
//
#include <hip/hip_runtime.h>
#include <math.h>

#define D_MODEL 1024
#define N_TOK   8192
#define SEQ_L   1024
#define N_HEAD  16
#define HEAD_D  64
#define FF_DIM  4096

typedef __attribute__((ext_vector_type(8))) short bf16x8;   // 8 bf16 = 4 VGPRs
typedef __attribute__((ext_vector_type(4))) short short4v;
typedef __attribute__((ext_vector_type(2))) int  int2v;
typedef __attribute__((ext_vector_type(4))) float f32x4;

#define MFMA16(a, b, c) __builtin_amdgcn_mfma_f32_16x16x32_bf16((a), (b), (c), 0, 0, 0)

// async global->LDS, 16B per lane; LDS dest = wave-uniform base + lane*16
#define GLD16(gp, lp) __builtin_amdgcn_global_load_lds(                      \
    (const __attribute__((address_space(1))) void*)(gp),                     \
    (__attribute__((address_space(3))) void*)(lp), 16, 0, 0)

#if defined(__has_builtin)
#if __has_builtin(__builtin_amdgcn_exp2f)
#define EXP2F(x) __builtin_amdgcn_exp2f(x)
#else
#define EXP2F(x) exp2f(x)
#endif
#else
#define EXP2F(x) exp2f(x)
#endif

__device__ __forceinline__ short f2bf(float f) {   // fp32 -> bf16 (RNE)
    unsigned u = __float_as_uint(f);
    u += 0x7fffu + ((u >> 16) & 1u);
    return (short)(u >> 16);
}

// pack two fp32 -> two bf16 (round-nearest-up) in one v_perm
__device__ __forceinline__ int pack2bf(float a, float b) {
    unsigned ua = __float_as_uint(a) + 0x8000u;
    unsigned ub = __float_as_uint(b) + 0x8000u;
    return __builtin_amdgcn_perm(ub, ua, 0x07060302u);
}

// LDS byte offset of a __shared__ address (addrspacecast -> 32-bit)
__device__ __forceinline__ unsigned ldsoff(const void* p) {
    return (unsigned)(size_t)(const __attribute__((address_space(3))) void*)p;
}

// inline-asm ds_read_b128: INVISIBLE to the compiler's waitcnt pass, so no
// spurious s_waitcnt vmcnt(0) is inserted against in-flight global_load_lds.
// MUST be followed (before use) by s_waitcnt lgkmcnt(0) + sched_barrier(0).
__device__ __forceinline__ bf16x8 dsr(unsigned off) {
    bf16x8 d;
    asm volatile("ds_read_b128 %0, %1" : "=v"(d) : "v"(off));
    return d;
}

// ---------------------------------------------------------------------------
// LayerNorm fp32 -> bf16. One block (256 thr) per token.
// ---------------------------------------------------------------------------
__global__ __launch_bounds__(256) void ln_kernel(const float* __restrict__ x,
                                                 const float* __restrict__ g,
                                                 const float* __restrict__ b,
                                                 short* __restrict__ o)
{
    int t = blockIdx.x;
    const float* xr = x + (size_t)t * D_MODEL;
    short* orow = o + (size_t)t * D_MODEL;
    float vals[4];
    float lsum = 0.f, lsq = 0.f;
#pragma unroll
    for (int i = 0; i < 4; i++) {
        float v = xr[threadIdx.x + i * 256];
        vals[i] = v; lsum += v; lsq += v * v;
    }
#pragma unroll
    for (int off = 32; off > 0; off >>= 1) {
        lsum += __shfl_down(lsum, off);
        lsq  += __shfl_down(lsq,  off);
    }
    __shared__ float red[8];
    int wid = threadIdx.x >> 6, lane = threadIdx.x & 63;
    if (lane == 0) { red[wid] = lsum; red[4 + wid] = lsq; }
    __syncthreads();
    if (threadIdx.x == 0) {
        red[0] = red[0] + red[1] + red[2] + red[3];
        red[4] = red[4] + red[5] + red[6] + red[7];
    }
    __syncthreads();
    float mean = red[0] * (1.f / D_MODEL);
    float var  = red[4] * (1.f / D_MODEL) - mean * mean;
    float inv  = rsqrtf(var + 1e-5f);
#pragma unroll
    for (int i = 0; i < 4; i++) {
        int c = threadIdx.x + i * 256;
        orow[c] = f2bf((vals[i] - mean) * inv * g[c] + b[c]);
    }
}

// ---------------------------------------------------------------------------
// Fused prep: six W [K,N] fp32 -> W^T [N,K] bf16 transposes + fp32 mask.
// ---------------------------------------------------------------------------
__global__ __launch_bounds__(256) void prep_kernel(
    const float* __restrict__ wq, const float* __restrict__ wk,
    const float* __restrict__ wv, const float* __restrict__ wo,
    const float* __restrict__ w1, const float* __restrict__ w2,
    const int*   __restrict__ amask,
    short* __restrict__ wqkvt, short* __restrict__ wot,
    short* __restrict__ w1t,  short* __restrict__ w2t,
    float* __restrict__ fmask)
{
    int id = blockIdx.x;
    if (id >= 12288) {   // mask job: 32 blocks x 256 = 8192 entries
        int i = (id - 12288) * 256 + threadIdx.x;
        fmask[i] = (amask[i] > 0) ? 0.f : -1e30f;
        return;
    }
    const float* src; short* dst; int R, C, tloc, csh;
    if (id < 4096) {
        int wsel = id >> 10; tloc = id & 1023; R = 1024; C = 1024; csh = 5;
        src = (wsel == 0) ? wq : (wsel == 1) ? wk : (wsel == 2) ? wv : wo;
        dst = (wsel == 3) ? wot : (wqkvt + (size_t)wsel * 1024 * 1024);
    } else if (id < 8192) {
        tloc = id - 4096; R = 1024; C = 4096; csh = 7; src = w1; dst = w1t;
    } else {
        tloc = id - 8192; R = 4096; C = 1024; csh = 5; src = w2; dst = w2t;
    }
    int ty = tloc >> csh, tx = tloc & ((1 << csh) - 1);
    int r0 = ty * 32, c0 = tx * 32;
    __shared__ float t[32][33];
    int tid = threadIdx.x;
#pragma unroll
    for (int i = 0; i < 4; i++) {
        int idx = i * 256 + tid;
        int r = idx >> 5, c = idx & 31;
        t[r][c] = src[(size_t)(r0 + r) * C + c0 + c];
    }
    __syncthreads();
#pragma unroll
    for (int i = 0; i < 4; i++) {
        int idx = i * 256 + tid;
        int rr = idx >> 5, cc = idx & 31;
        dst[(size_t)(c0 + rr) * R + r0 + cc] = f2bf(t[cc][rr]);
    }
}

// ---------------------------------------------------------------------------
// Legacy 128x128 GEMM — QKV (single-buffer) and O-proj (dbuf).
// ---------------------------------------------------------------------------
template<int DBUF>
__global__ __launch_bounds__(256) void gemm_bf16(
    const short* __restrict__ A, int lda,
    const short* __restrict__ Bt, int ldb,
    const float* __restrict__ bias,
    const float* __restrict__ bias2,
    const float* __restrict__ bias3,
    const float* __restrict__ resid,
    float* __restrict__ Cf, short* __restrict__ Cb, short* __restrict__ Cvt,
    int ldc, int K, int act, int qkv, int gx)
{
    __shared__ __align__(16) short sA[(1 + DBUF) * 8192];   // swizzled
    __shared__ __align__(16) short sB[(1 + DBUF) * 8192];
    const int tid = threadIdx.x;
    const int lane = tid & 63, wave = tid >> 6;
    const int quad = lane >> 4, l15 = lane & 15;

    const int id = blockIdx.x;
    const int xcd = id & 7, j = id >> 3;
    const int bx = j % gx, by = xcd + 8 * (j / gx);
    const int bm = by * 128, bn = bx * 128;
    const int wm = (wave >> 1) * 64, wn = (wave & 1) * 64;

    const int lr = lane >> 3;            // 0..7 row within an 8-row call
    const int lc = (lane & 7) ^ lr;      // chunk ^ (row&7)
    const int sw = l15 & 7;              // read-side swizzle key

    const short* Ab = A  + (size_t)(bm + wave * 32 + lr) * lda + lc * 8;
    const short* Bb = Bt + (size_t)(bn + wave * 32 + lr) * ldb + lc * 8;

    f32x4 acc[4][4];
#pragma unroll
    for (int i = 0; i < 4; i++)
#pragma unroll
        for (int jj = 0; jj < 4; jj++) acc[i][jj] = (f32x4){0.f, 0.f, 0.f, 0.f};

    const int nk = K >> 6;

    if (DBUF) {
#pragma unroll
        for (int c = 0; c < 4; c++) {
            int cid = wave * 4 + c;
            GLD16(Ab + (size_t)(c * 8) * lda, &sA[cid * 512]);
            GLD16(Bb + (size_t)(c * 8) * ldb, &sB[cid * 512]);
        }
    }

    for (int ki = 0; ki < nk; ki++) {
        __syncthreads();
        if (DBUF) {
            if (ki + 1 < nk) {
                int k0 = (ki + 1) << 6, nb = (ki + 1) & 1;
#pragma unroll
                for (int c = 0; c < 4; c++) {
                    int cid = wave * 4 + c;
                    GLD16(Ab + (size_t)(c * 8) * lda + k0, &sA[nb * 8192 + cid * 512]);
                    GLD16(Bb + (size_t)(c * 8) * ldb + k0, &sB[nb * 8192 + cid * 512]);
                }
            }
        } else {
            int k0 = ki << 6;
#pragma unroll
            for (int c = 0; c < 4; c++) {
                int cid = wave * 4 + c;
                GLD16(Ab + (size_t)(c * 8) * lda + k0, &sA[cid * 512]);
                GLD16(Bb + (size_t)(c * 8) * ldb + k0, &sB[cid * 512]);
            }
            __syncthreads();
        }
        const short* cA = &sA[DBUF ? (ki & 1) * 8192 : 0];
        const short* cB = &sB[DBUF ? (ki & 1) * 8192 : 0];
#pragma unroll
        for (int ko = 0; ko < 2; ko++) {
            bf16x8 af[4], bfr[4];
#pragma unroll
            for (int mt = 0; mt < 4; mt++) {
                int row = wm + mt * 16 + l15;
                af[mt] = *(const bf16x8*)&cA[(row * 8 + ((ko * 4 + quad) ^ sw)) * 8];
            }
#pragma unroll
            for (int nt = 0; nt < 4; nt++) {
                int row = wn + nt * 16 + l15;
                bfr[nt] = *(const bf16x8*)&cB[(row * 8 + ((ko * 4 + quad) ^ sw)) * 8];
            }
#pragma unroll
            for (int mt = 0; mt < 4; mt++)
#pragma unroll
                for (int nt = 0; nt < 4; nt++)
                    acc[mt][nt] = MFMA16(af[mt], bfr[nt], acc[mt][nt]);
        }
    }

#pragma unroll
    for (int mt = 0; mt < 4; mt++)
#pragma unroll
        for (int nt = 0; nt < 4; nt++) {
            int row0 = bm + wm + mt * 16 + quad * 4;
            int col  = bn + wn + nt * 16 + l15;
            if (qkv) {
                int seg = col >> 10, cloc = col & 1023;
                const float* bp = (seg == 0) ? bias : (seg == 1) ? bias2 : bias3;
                float bval = bp[cloc];
                if (seg == 2) {
                    int bb = row0 >> 10, l0 = row0 & 1023;
                    size_t page = (size_t)(bb * N_HEAD + (cloc >> 6)) * HEAD_D + (cloc & 63);
                    short4v pk = { f2bf(acc[mt][nt][0] + bval), f2bf(acc[mt][nt][1] + bval),
                                   f2bf(acc[mt][nt][2] + bval), f2bf(acc[mt][nt][3] + bval) };
                    *(short4v*)&Cvt[page * SEQ_L + l0] = pk;
                } else {
                    short* dst = Cb + (size_t)seg * ((size_t)N_TOK * D_MODEL);
#pragma unroll
                    for (int r = 0; r < 4; r++)
                        dst[(size_t)(row0 + r) * D_MODEL + cloc] = f2bf(acc[mt][nt][r] + bval);
                }
            } else {
#pragma unroll
                for (int r = 0; r < 4; r++) {
                    int row = row0 + r;
                    float v = acc[mt][nt][r] + bias[col];
                    if (act) v = v / (1.f + __expf(-1.702f * v));   // quick_gelu
                    if (resid) v += resid[(size_t)row * ldc + col];
                    if (Cb) Cb[(size_t)row * ldc + col] = f2bf(v);
                    else    Cf[(size_t)row * ldc + col] = v;
                }
            }
        }
}

// ---------------------------------------------------------------------------
// 256x256 (NREP=4) / 256x128 (NREP=2) 8-phase GEMM, BK=64, 512 thr = 8 waves.
// v2: ALL LDS fragment reads are inline-asm ds_read_b128 (invisible to the
// compiler waitcnt pass -> no spurious vmcnt(0) drains); explicit
// lgkmcnt(0)+sched_barrier(0) before each consuming MFMA cluster (rule #18).
// Counted vmcnt only at PH4/PH8; raw s_barrier; setprio around MFMA.
//
// Stage schedule (tile t in buf0, t+1 in buf1), per 2 K-tiles:
//   ph1:(t+1).A1  ph2:(t+2).B0  ph3:(t+2).B1  ph4:(t+2).A0 [vmcnt]
//   ph5:(t+2).A1  ph6:(t+3).B0  ph7:(t+3).B1  ph8:(t+3).A0 [vmcnt]
// Read schedule (every phase's read region disjoint from its stage region):
//   ph1: B_lo + A m0-3   ph2: B_hi (NREP=4 only)   ph3: A m4-7   ph4: none
// Every region's last reader-phase strictly precedes its re-stage phase.
// ---------------------------------------------------------------------------
#define BAR() __builtin_amdgcn_s_barrier()
#define WAIT_LGKM0() do { asm volatile("s_waitcnt lgkmcnt(0)");               \
                          __builtin_amdgcn_sched_barrier(0); } while (0)

#define STA(buf, h, tt) do {                                                  \
    const short* s_ = Asrc + (size_t)((h) * 128) * lda + (size_t)(tt) * 64;   \
    GLD16(s_,                    &sAs[(buf)*16384 + (h)*8192        + wave*512]); \
    GLD16(s_ + (size_t)64 * lda, &sAs[(buf)*16384 + (h)*8192 + 4096 + wave*512]); \
} while (0)

#define STB(buf, h, tt) do {                                                  \
    if constexpr (NREP == 4) {                                                \
        const short* s_ = Bsrc + (size_t)((h) * 128) * ldb + (size_t)(tt) * 64; \
        GLD16(s_,                    &sBs[(buf)*16384 + (h)*8192        + wave*512]); \
        GLD16(s_ + (size_t)64 * ldb, &sBs[(buf)*16384 + (h)*8192 + 4096 + wave*512]); \
    } else {                                                                  \
        const short* s_ = Bsrc + (size_t)((h) * 64) * ldb + (size_t)(tt) * 64; \
        GLD16(s_, &sBs[(buf)*8192 + (h)*4096 + wave*512]);                    \
    }                                                                         \
} while (0)

#define VMCNT() do {                                                          \
    if constexpr (NREP == 4) asm volatile("s_waitcnt vmcnt(6)");              \
    else                     asm volatile("s_waitcnt vmcnt(4)");              \
} while (0)

// asm LDS reads: byte addr = base + buf*bytes + row*128 + chunk*16
#define RDB(buf, nt) do {                                                     \
    unsigned r_ = bBase + (buf) * BUFB + ((unsigned)(wn + (nt)*16 + l15) << 7); \
    bfr[nt][0] = dsr(r_ + c0); bfr[nt][1] = dsr(r_ + c1);                     \
} while (0)
#define RDA(buf, mt8) do {                                                    \
    unsigned r_ = aBase + (buf) * 32768u + ((unsigned)(wm + (mt8)*16 + l15) << 7); \
    afr[(mt8) & 3][0] = dsr(r_ + c0); afr[(mt8) & 3][1] = dsr(r_ + c1);       \
} while (0)

#define PH_MFMA(mh, nh)                                                       \
    __builtin_amdgcn_s_setprio(1);                                            \
    _Pragma("unroll")                                                         \
    for (int mt = 0; mt < 4; mt++)                                            \
        _Pragma("unroll")                                                     \
        for (int nt = 0; nt < NREP / 2; nt++) {                               \
            acc[(mh)*4 + mt][(nh)*(NREP/2) + nt] =                            \
                MFMA16(afr[mt][0], bfr[(nh)*(NREP/2) + nt][0],                \
                       acc[(mh)*4 + mt][(nh)*(NREP/2) + nt]);                 \
            acc[(mh)*4 + mt][(nh)*(NREP/2) + nt] =                            \
                MFMA16(afr[mt][1], bfr[(nh)*(NREP/2) + nt][1],                \
                       acc[(mh)*4 + mt][(nh)*(NREP/2) + nt]);                 \
        }                                                                     \
    __builtin_amdgcn_s_setprio(0);

template<int NREP>   // NREP=4 -> BN=256, NREP=2 -> BN=128
__global__ __launch_bounds__(512, 2) void gemm256(
    const short* __restrict__ A, int lda,
    const short* __restrict__ Bt, int ldb,
    const float* __restrict__ bias,
    const float* __restrict__ bias2,
    const float* __restrict__ bias3,
    const float* __restrict__ resid,
    float* __restrict__ Cf, short* __restrict__ Cb, short* __restrict__ Cvt,
    int ldc, int K, int act, int qkv, int gx)
{
    constexpr int BN = NREP * 64;
    constexpr unsigned BUFB = (unsigned)BN * 64u * 2u;   // B bytes/buf
    __shared__ __align__(16) short sAs[2 * 256 * 64];    // 64 KB, dbuf
    __shared__ __align__(16) short sBs[2 * BN  * 64];    // 64/32 KB, dbuf

    const int tid  = threadIdx.x;
    const int wave = tid >> 6, lane = tid & 63;
    const int quad = lane >> 4, l15 = lane & 15;
    const int wm = (wave >> 2) * 128;            // warp_m * 128
    const int wn = (wave & 3) * (NREP * 16);     // warp_n * per-wave N
    const int sw = l15 & 7;

    const unsigned aBase = ldsoff(sAs);
    const unsigned bBase = ldsoff(sBs);
    const unsigned c0 = (unsigned)((quad ^ sw) << 4);
    const unsigned c1 = c0 ^ 64u;

    // XCD row-panel swizzle
    const int id = blockIdx.x;
    const int xcd = id & 7, j = id >> 3;
    const int bx = j % gx, by = xcd + 8 * (j / gx);
    const int bm = by * 256, bn = bx * BN;

    // staging: thread covers (row = tid>>3, chunk = (tid&7)^(row&7)) of a
    // 64-row half-stage; source pre-swizzled so linear LDS dest == swizzled.
    const int r_in = tid >> 3;
    const int csrc = (tid & 7) ^ (r_in & 7);
    const short* Asrc = A  + (size_t)(bm + r_in) * lda + csrc * 8;
    const short* Bsrc = Bt + (size_t)(bn + r_in) * ldb + csrc * 8;

    f32x4 acc[8][NREP];
#pragma unroll
    for (int i = 0; i < 8; i++)
#pragma unroll
        for (int jj = 0; jj < NREP; jj++) acc[i][jj] = (f32x4){0.f, 0.f, 0.f, 0.f};

    const int nk = K >> 6;

    // prologue: tile0 full + tile1 (B0,B1,A0); wait until tile0 landed
    STB(0, 0, 0); STB(0, 1, 0);
    STA(0, 0, 0); STA(0, 1, 0);
    STB(1, 0, 1); STB(1, 1, 1);
    STA(1, 0, 1);
    VMCNT();
    BAR();

    bf16x8 afr[4][2], bfr[NREP][2];

    for (int it = 0; it < nk; it += 2) {
        int t2 = it + 2; if (t2 >= nk) t2 -= nk;   // wrapped dummy stages keep
        int t3 = it + 3; if (t3 >= nk) t3 -= nk;   // vmcnt counts uniform

        // -------- PH1: tile t (buf0): m0-3 x nlo --------
        RDB(0, 0); RDB(0, 1);
        RDA(0, 0); RDA(0, 1); RDA(0, 2); RDA(0, 3);
        STA(1, 1, it + 1);
        BAR(); WAIT_LGKM0();
        PH_MFMA(0, 0);
        BAR();
        // -------- PH2: m0-3 x nhi --------
        if constexpr (NREP == 4) { RDB(0, 2); RDB(0, 3); }
        STB(0, 0, t2);
        BAR();
        if constexpr (NREP == 4) WAIT_LGKM0();
        PH_MFMA(0, 1);
        BAR();
        // -------- PH3: m4-7 x nhi --------
        RDA(0, 4); RDA(0, 5); RDA(0, 6); RDA(0, 7);
        STB(0, 1, t2);
        BAR(); WAIT_LGKM0();
        PH_MFMA(1, 1);
        BAR();
        // -------- PH4: m4-7 x nlo, counted vmcnt --------
        STA(0, 0, t2);
        BAR();
        PH_MFMA(1, 0);
        VMCNT();
        BAR();
        // -------- PH5: tile t+1 (buf1): m0-3 x nlo --------
        RDB(1, 0); RDB(1, 1);
        RDA(1, 0); RDA(1, 1); RDA(1, 2); RDA(1, 3);
        STA(0, 1, t2);
        BAR(); WAIT_LGKM0();
        PH_MFMA(0, 0);
        BAR();
        // -------- PH6: m0-3 x nhi --------
        if constexpr (NREP == 4) { RDB(1, 2); RDB(1, 3); }
        STB(1, 0, t3);
        BAR();
        if constexpr (NREP == 4) WAIT_LGKM0();
        PH_MFMA(0, 1);
        BAR();
        // -------- PH7: m4-7 x nhi --------
        RDA(1, 4); RDA(1, 5); RDA(1, 6); RDA(1, 7);
        STB(1, 1, t3);
        BAR(); WAIT_LGKM0();
        PH_MFMA(1, 1);
        BAR();
        // -------- PH8: m4-7 x nlo, counted vmcnt --------
        STA(1, 0, t3);
        BAR();
        PH_MFMA(1, 0);
        VMCNT();
        BAR();
    }

    // epilogue (C/D mapping: col=lane&15, row=quad*4+r)
#pragma unroll
    for (int mt = 0; mt < 8; mt++)
#pragma unroll
        for (int nt = 0; nt < NREP; nt++) {
            int row0 = bm + wm + mt * 16 + quad * 4;
            int col  = bn + wn + nt * 16 + l15;
            if (qkv) {
                int seg = col >> 10, cloc = col & 1023;
                const float* bp = (seg == 0) ? bias : (seg == 1) ? bias2 : bias3;
                float bval = bp[cloc];
                if (seg == 2) {
                    int bb = row0 >> 10, l0 = row0 & 1023;
                    size_t page = (size_t)(bb * N_HEAD + (cloc >> 6)) * HEAD_D + (cloc & 63);
                    short4v pk = { f2bf(acc[mt][nt][0] + bval), f2bf(acc[mt][nt][1] + bval),
                                   f2bf(acc[mt][nt][2] + bval), f2bf(acc[mt][nt][3] + bval) };
                    *(short4v*)&Cvt[page * SEQ_L + l0] = pk;
                } else {
                    short* dst = Cb + (size_t)seg * ((size_t)N_TOK * D_MODEL);
#pragma unroll
                    for (int r = 0; r < 4; r++)
                        dst[(size_t)(row0 + r) * D_MODEL + cloc] = f2bf(acc[mt][nt][r] + bval);
                }
            } else {
#pragma unroll
                for (int r = 0; r < 4; r++) {
                    int row = row0 + r;
                    float v = acc[mt][nt][r] + bias[col];
                    if (act) v = v / (1.f + __expf(-1.702f * v));   // quick_gelu
                    if (resid) v += resid[(size_t)row * ldc + col];
                    if (Cb) Cb[(size_t)row * ldc + col] = f2bf(v);
                    else    Cf[(size_t)row * ldc + col] = v;
                }
            }
        }
}

// ---------------------------------------------------------------------------
// Flash attention, 128 q-rows/block (unchanged).
// ---------------------------------------------------------------------------
__global__ __launch_bounds__(256) void attn_kernel(
    const short* __restrict__ Q, const short* __restrict__ Kb,
    const short* __restrict__ Vt, const float* __restrict__ fmask,
    short* __restrict__ O)
{
    __shared__ __align__(16) short sK[8192];        // 16KB: slot=kc*128+key
    __shared__ __align__(16) short sV[8192];        // 16KB: slot=kc2*64+d
    __shared__ __align__(16) short sP[4][32 * 136]; // per-wave [32 q][136]
    __shared__ __align__(16) float sAl[4][2][20];

    const int g = blockIdx.x;
    const int xcd = g & 7, slot = g >> 3;
    const int qt = slot & 7, bhl = slot >> 3;
    const int bh = xcd * 16 + bhl;
    const int b = bh >> 4, h = bh & 15;

    const int tid = threadIdx.x;
    const int wave = tid >> 6, lane = tid & 63;
    const int quad = lane >> 4, l15 = lane & 15;

    const int qbase = b * SEQ_L + qt * 128;
    bf16x8 qf[2][2];
#pragma unroll
    for (int qh = 0; qh < 2; qh++) {
        const short* qp = Q + (size_t)(qbase + wave * 32 + qh * 16 + l15) * D_MODEL
                        + h * HEAD_D + quad * 8;
        qf[qh][0] = *(const bf16x8*)qp;
        qf[qh][1] = *(const bf16x8*)(qp + 32);
    }

    const short* Kbh = Kb + (size_t)b * SEQ_L * D_MODEL + h * HEAD_D;
    const short* Vbh = Vt + (size_t)(b * N_HEAD + h) * HEAD_D * SEQ_L;
    const float* mk  = fmask + b * SEQ_L;

    f32x4 o4[2][4];
#pragma unroll
    for (int qh = 0; qh < 2; qh++)
#pragma unroll
        for (int nt = 0; nt < 4; nt++) o4[qh][nt] = (f32x4){0.f, 0.f, 0.f, 0.f};
    float mrow[2] = {-1e30f, -1e30f}, lrow[2] = {0.f, 0.f};
    short* pslab = &sP[wave][0];         // per-wave private [32 q][136]
    const float CSC = 0.125f * 1.4426950408889634f;   // scale * log2(e)

    for (int kt = 0; kt < SEQ_L / 128; kt++) {
        __syncthreads();   // previous iter's frag reads done
#pragma unroll
        for (int j = 0; j < 4; j++) {
            int cid = wave * 4 + j;
            int kc = cid >> 1, key0 = (cid & 1) << 6;
            GLD16(Kbh + (size_t)(kt * 128 + key0 + lane) * D_MODEL + kc * 8,
                  &sK[cid * 512]);
            GLD16(Vbh + (size_t)lane * SEQ_L + kt * 128 + cid * 8,
                  &sV[cid * 512]);
        }
        __syncthreads();   // staging complete (vmcnt drained by barrier)

        f32x4 mkv[8];
#pragma unroll
        for (int sub = 0; sub < 8; sub++)
            mkv[sub] = *(const f32x4*)&mk[kt * 128 + sub * 16 + quad * 4];

        f32x4 s[8][2];
#pragma unroll
        for (int sub = 0; sub < 8; sub++) {
            bf16x8 kf0 = *(const bf16x8*)&sK[(quad * 128 + sub * 16 + l15) * 8];
            bf16x8 kf1 = *(const bf16x8*)&sK[((quad + 4) * 128 + sub * 16 + l15) * 8];
#pragma unroll
            for (int qh = 0; qh < 2; qh++) {
                s[sub][qh] = (f32x4){0.f, 0.f, 0.f, 0.f};
                s[sub][qh] = MFMA16(kf0, qf[qh][0], s[sub][qh]);
                s[sub][qh] = MFMA16(kf1, qf[qh][1], s[sub][qh]);
            }
        }
        float alpha[2];
#pragma unroll
        for (int qh = 0; qh < 2; qh++) {
#pragma unroll
            for (int sub = 0; sub < 8; sub++)
#pragma unroll
                for (int r = 0; r < 4; r++)
                    s[sub][qh][r] = s[sub][qh][r] * CSC + mkv[sub][r];
            f32x4 mx4 = s[0][qh];
#pragma unroll
            for (int sub = 1; sub < 8; sub++)
#pragma unroll
                for (int r = 0; r < 4; r++) mx4[r] = fmaxf(mx4[r], s[sub][qh][r]);
            float pmax = fmaxf(fmaxf(mx4[0], mx4[1]), fmaxf(mx4[2], mx4[3]));
            pmax = fmaxf(pmax, __shfl_xor(pmax, 16));
            pmax = fmaxf(pmax, __shfl_xor(pmax, 32));
            float mnew = fmaxf(mrow[qh], pmax);
            alpha[qh] = EXP2F(mrow[qh] - mnew);
            mrow[qh] = mnew;
            if (quad == 0) sAl[wave][qh][l15] = alpha[qh];

            float ls = 0.f;
#pragma unroll
            for (int sub = 0; sub < 8; sub++) {
                float p0 = EXP2F(s[sub][qh][0] - mnew);
                float p1 = EXP2F(s[sub][qh][1] - mnew);
                float p2 = EXP2F(s[sub][qh][2] - mnew);
                float p3 = EXP2F(s[sub][qh][3] - mnew);
                ls += (p0 + p1) + (p2 + p3);
                int2v pk = { pack2bf(p0, p1), pack2bf(p2, p3) };
                *(int2v*)&pslab[(qh * 16 + l15) * 136 + sub * 16 + quad * 4] = pk;
            }
            ls += __shfl_xor(ls, 16);
            ls += __shfl_xor(ls, 32);
            lrow[qh] = lrow[qh] * alpha[qh] + ls;
        }

#pragma unroll
        for (int qh = 0; qh < 2; qh++) {
            f32x4 av = *(const f32x4*)&sAl[wave][qh][quad * 4];
#pragma unroll
            for (int nt = 0; nt < 4; nt++)
#pragma unroll
                for (int r = 0; r < 4; r++) o4[qh][nt][r] *= av[r];
        }

        bf16x8 pf[2][4];
#pragma unroll
        for (int qh = 0; qh < 2; qh++)
#pragma unroll
            for (int c = 0; c < 4; c++)
                pf[qh][c] = *(const bf16x8*)&pslab[(qh * 16 + l15) * 136 + c * 32 + quad * 8];
#pragma unroll
        for (int nt = 0; nt < 4; nt++)
#pragma unroll
            for (int c = 0; c < 4; c++) {
                bf16x8 vfr = *(const bf16x8*)&sV[((c * 4 + quad) * 64 + nt * 16 + l15) * 8];
                o4[0][nt] = MFMA16(pf[0][c], vfr, o4[0][nt]);
                o4[1][nt] = MFMA16(pf[1][c], vfr, o4[1][nt]);
            }
    }
    if (quad == 0) {
        sAl[wave][0][l15] = 1.f / lrow[0];
        sAl[wave][1][l15] = 1.f / lrow[1];
    }
    __syncthreads();
#pragma unroll
    for (int qh = 0; qh < 2; qh++) {
        f32x4 iv = *(const f32x4*)&sAl[wave][qh][quad * 4];
#pragma unroll
        for (int nt = 0; nt < 4; nt++)
#pragma unroll
            for (int r = 0; r < 4; r++)
                O[(size_t)(qbase + wave * 32 + qh * 16 + quad * 4 + r) * D_MODEL
                  + h * HEAD_D + nt * 16 + l15] = f2bf(o4[qh][nt][r] * iv[r]);
    }
}

// ---------------------------------------------------------------------------
// Launch
// ---------------------------------------------------------------------------
extern "C" void kernel_launch(void* const* d_in, const int* in_sizes, int n_in,
                              void* d_out, int out_size, void* d_ws, size_t ws_size,
                              hipStream_t stream)
{
    const float* x     = (const float*)d_in[0];
    const int*   amask = (const int*)  d_in[1];
    const float* wq    = (const float*)d_in[2];
    const float* bq    = (const float*)d_in[3];
    const float* wk    = (const float*)d_in[4];
    const float* bk    = (const float*)d_in[5];
    const float* wv    = (const float*)d_in[6];
    const float* bv    = (const float*)d_in[7];
    const float* wo    = (const float*)d_in[8];
    const float* bo    = (const float*)d_in[9];
    const float* ln1s  = (const float*)d_in[10];
    const float* ln1b  = (const float*)d_in[11];
    const float* ln2s  = (const float*)d_in[12];
    const float* ln2b  = (const float*)d_in[13];
    const float* w1    = (const float*)d_in[14];
    const float* b1    = (const float*)d_in[15];
    const float* w2    = (const float*)d_in[16];
    const float* b2    = (const float*)d_in[17];
    float* out = (float*)d_out;

    char* w = (char*)d_ws;
    short* wqkvt = (short*)(w + (size_t)0);          // [3072][1024] bf16, 6MB
    short* wot   = (short*)(w + ((size_t)6  << 20));
    short* w1t   = (short*)(w + ((size_t)8  << 20));
    short* w2t   = (short*)(w + ((size_t)16 << 20));
    short* hb    = (short*)(w + ((size_t)24 << 20)); // LN1 out, later LN2 out
    short* qb    = (short*)(w + ((size_t)40 << 20)); // qb,kbf contiguous:
    short* kbf   = (short*)(w + ((size_t)56 << 20)); //   16MB stride for qkv mode
    short* attnb = (short*)(w + ((size_t)72 << 20));
    short* vtb   = (short*)(w + ((size_t)88 << 20));
    short* ffb   = qb;   // q/k/vt dead by MLP1 (64 MB span 40..104)
    float* fmaskb = (float*)d_out;

    dim3 blk(256), blk512(512);

    prep_kernel<<<dim3(12320), blk, 0, stream>>>(wq, wk, wv, wo, w1, w2, amask,
                                                 wqkvt, wot, w1t, w2t, fmaskb);

    // 1) h = LN1(x) -> bf16
    ln_kernel<<<N_TOK, blk, 0, stream>>>(x, ln1s, ln1b, hb);

    // 2) fused QKV GEMM: legacy 128^2 single-buffer (proven 80us)
    gemm_bf16<0><<<dim3(24 * 64), blk, 0, stream>>>(
        hb, 1024, wqkvt, 1024, bq, bk, bv, nullptr,
        nullptr, qb, vtb, 1024, 1024, 0, 1, 24);

    // 3) flash attention -> attnb (bf16)
    attn_kernel<<<dim3(1024), blk, 0, stream>>>(qb, kbf, vtb, fmaskb, attnb);

    // 4) out = x + attn @ wo + bo  (legacy dbuf-128^2)
    gemm_bf16<1><<<dim3(8 * 64), blk, 0, stream>>>(
        attnb, 1024, wot, 1024, bo, nullptr, nullptr, x,
        out, nullptr, nullptr, 1024, 1024, 0, 0, 8);

    // 5) h = LN2(out) -> bf16
    ln_kernel<<<N_TOK, blk, 0, stream>>>(out, ln2s, ln2b, hb);

    // 6) MLP1: 256^2 8-phase v2, grid 16x32 = 512; MLP2: 256x128 v2, 8x32 = 256
    gemm256<4><<<dim3(512), blk512, 0, stream>>>(
        hb, 1024, w1t, 1024, b1, nullptr, nullptr, nullptr,
        nullptr, ffb, nullptr, 4096, 1024, 1, 0, 16);
    gemm256<2><<<dim3(256), blk512, 0, stream>>>(
        ffb, 4096, w2t, 4096, b2, nullptr, nullptr, out,
        out, nullptr, nullptr, 1024, 4096, 0, 0, 8);
}

// Round 3
// 590.716 us; speedup vs baseline: 1.2666x; 1.0365x over previous
//
#include <hip/hip_runtime.h>
#include <math.h>

#define D_MODEL 1024
#define N_TOK   8192
#define SEQ_L   1024
#define N_HEAD  16
#define HEAD_D  64
#define FF_DIM  4096

typedef __attribute__((ext_vector_type(8))) short bf16x8;   // 8 bf16 = 4 VGPRs
typedef __attribute__((ext_vector_type(4))) short short4v;
typedef __attribute__((ext_vector_type(2))) int  int2v;
typedef __attribute__((ext_vector_type(4))) float f32x4;

#define MFMA16(a, b, c) __builtin_amdgcn_mfma_f32_16x16x32_bf16((a), (b), (c), 0, 0, 0)

// async global->LDS, 16B per lane; LDS dest = wave-uniform base + lane*16
#define GLD16(gp, lp) __builtin_amdgcn_global_load_lds(                      \
    (const __attribute__((address_space(1))) void*)(gp),                     \
    (__attribute__((address_space(3))) void*)(lp), 16, 0, 0)

#if defined(__has_builtin)
#if __has_builtin(__builtin_amdgcn_exp2f)
#define EXP2F(x) __builtin_amdgcn_exp2f(x)
#else
#define EXP2F(x) exp2f(x)
#endif
#else
#define EXP2F(x) exp2f(x)
#endif

__device__ __forceinline__ short f2bf(float f) {   // fp32 -> bf16 (RNE)
    unsigned u = __float_as_uint(f);
    u += 0x7fffu + ((u >> 16) & 1u);
    return (short)(u >> 16);
}

// pack two fp32 -> two bf16 (round-nearest-up) in one v_perm
__device__ __forceinline__ int pack2bf(float a, float b) {
    unsigned ua = __float_as_uint(a) + 0x8000u;
    unsigned ub = __float_as_uint(b) + 0x8000u;
    return __builtin_amdgcn_perm(ub, ua, 0x07060302u);
}

// LDS byte offset of a __shared__ address (addrspacecast -> 32-bit)
__device__ __forceinline__ unsigned ldsoff(const void* p) {
    return (unsigned)(size_t)(const __attribute__((address_space(3))) void*)p;
}

// inline-asm ds_read_b128 (invisible to waitcnt pass); follow with
// s_waitcnt lgkmcnt(0) + sched_barrier(0) before use (rule #18).
__device__ __forceinline__ bf16x8 dsr(unsigned off) {
    bf16x8 d;
    asm volatile("ds_read_b128 %0, %1" : "=v"(d) : "v"(off));
    return d;
}

// ---------------------------------------------------------------------------
// LayerNorm fp32 -> bf16. One block (256 thr) per token.
// ---------------------------------------------------------------------------
__global__ __launch_bounds__(256) void ln_kernel(const float* __restrict__ x,
                                                 const float* __restrict__ g,
                                                 const float* __restrict__ b,
                                                 short* __restrict__ o)
{
    int t = blockIdx.x;
    const float* xr = x + (size_t)t * D_MODEL;
    short* orow = o + (size_t)t * D_MODEL;
    float vals[4];
    float lsum = 0.f, lsq = 0.f;
#pragma unroll
    for (int i = 0; i < 4; i++) {
        float v = xr[threadIdx.x + i * 256];
        vals[i] = v; lsum += v; lsq += v * v;
    }
#pragma unroll
    for (int off = 32; off > 0; off >>= 1) {
        lsum += __shfl_down(lsum, off);
        lsq  += __shfl_down(lsq,  off);
    }
    __shared__ float red[8];
    int wid = threadIdx.x >> 6, lane = threadIdx.x & 63;
    if (lane == 0) { red[wid] = lsum; red[4 + wid] = lsq; }
    __syncthreads();
    if (threadIdx.x == 0) {
        red[0] = red[0] + red[1] + red[2] + red[3];
        red[4] = red[4] + red[5] + red[6] + red[7];
    }
    __syncthreads();
    float mean = red[0] * (1.f / D_MODEL);
    float var  = red[4] * (1.f / D_MODEL) - mean * mean;
    float inv  = rsqrtf(var + 1e-5f);
#pragma unroll
    for (int i = 0; i < 4; i++) {
        int c = threadIdx.x + i * 256;
        orow[c] = f2bf((vals[i] - mean) * inv * g[c] + b[c]);
    }
}

// ---------------------------------------------------------------------------
// Fused prep: six W [K,N] fp32 -> W^T [N,K] bf16 transposes + fp32 mask.
// ---------------------------------------------------------------------------
__global__ __launch_bounds__(256) void prep_kernel(
    const float* __restrict__ wq, const float* __restrict__ wk,
    const float* __restrict__ wv, const float* __restrict__ wo,
    const float* __restrict__ w1, const float* __restrict__ w2,
    const int*   __restrict__ amask,
    short* __restrict__ wqkvt, short* __restrict__ wot,
    short* __restrict__ w1t,  short* __restrict__ w2t,
    float* __restrict__ fmask)
{
    int id = blockIdx.x;
    if (id >= 12288) {   // mask job: 32 blocks x 256 = 8192 entries
        int i = (id - 12288) * 256 + threadIdx.x;
        fmask[i] = (amask[i] > 0) ? 0.f : -1e30f;
        return;
    }
    const float* src; short* dst; int R, C, tloc, csh;
    if (id < 4096) {
        int wsel = id >> 10; tloc = id & 1023; R = 1024; C = 1024; csh = 5;
        src = (wsel == 0) ? wq : (wsel == 1) ? wk : (wsel == 2) ? wv : wo;
        dst = (wsel == 3) ? wot : (wqkvt + (size_t)wsel * 1024 * 1024);
    } else if (id < 8192) {
        tloc = id - 4096; R = 1024; C = 4096; csh = 7; src = w1; dst = w1t;
    } else {
        tloc = id - 8192; R = 4096; C = 1024; csh = 5; src = w2; dst = w2t;
    }
    int ty = tloc >> csh, tx = tloc & ((1 << csh) - 1);
    int r0 = ty * 32, c0 = tx * 32;
    __shared__ float t[32][33];
    int tid = threadIdx.x;
#pragma unroll
    for (int i = 0; i < 4; i++) {
        int idx = i * 256 + tid;
        int r = idx >> 5, c = idx & 31;
        t[r][c] = src[(size_t)(r0 + r) * C + c0 + c];
    }
    __syncthreads();
#pragma unroll
    for (int i = 0; i < 4; i++) {
        int idx = i * 256 + tid;
        int rr = idx >> 5, cc = idx & 31;
        dst[(size_t)(c0 + rr) * R + r0 + cc] = f2bf(t[cc][rr]);
    }
}

// ---------------------------------------------------------------------------
// Legacy 128x128 GEMM — QKV (single-buffer) and O-proj (dbuf).
// ---------------------------------------------------------------------------
template<int DBUF>
__global__ __launch_bounds__(256) void gemm_bf16(
    const short* __restrict__ A, int lda,
    const short* __restrict__ Bt, int ldb,
    const float* __restrict__ bias,
    const float* __restrict__ bias2,
    const float* __restrict__ bias3,
    const float* __restrict__ resid,
    float* __restrict__ Cf, short* __restrict__ Cb, short* __restrict__ Cvt,
    int ldc, int K, int act, int qkv, int gx)
{
    __shared__ __align__(16) short sA[(1 + DBUF) * 8192];   // swizzled
    __shared__ __align__(16) short sB[(1 + DBUF) * 8192];
    const int tid = threadIdx.x;
    const int lane = tid & 63, wave = tid >> 6;
    const int quad = lane >> 4, l15 = lane & 15;

    const int id = blockIdx.x;
    const int xcd = id & 7, j = id >> 3;
    const int bx = j % gx, by = xcd + 8 * (j / gx);
    const int bm = by * 128, bn = bx * 128;
    const int wm = (wave >> 1) * 64, wn = (wave & 1) * 64;

    const int lr = lane >> 3;            // 0..7 row within an 8-row call
    const int lc = (lane & 7) ^ lr;      // chunk ^ (row&7)
    const int sw = l15 & 7;              // read-side swizzle key

    const short* Ab = A  + (size_t)(bm + wave * 32 + lr) * lda + lc * 8;
    const short* Bb = Bt + (size_t)(bn + wave * 32 + lr) * ldb + lc * 8;

    f32x4 acc[4][4];
#pragma unroll
    for (int i = 0; i < 4; i++)
#pragma unroll
        for (int jj = 0; jj < 4; jj++) acc[i][jj] = (f32x4){0.f, 0.f, 0.f, 0.f};

    const int nk = K >> 6;

    if (DBUF) {
#pragma unroll
        for (int c = 0; c < 4; c++) {
            int cid = wave * 4 + c;
            GLD16(Ab + (size_t)(c * 8) * lda, &sA[cid * 512]);
            GLD16(Bb + (size_t)(c * 8) * ldb, &sB[cid * 512]);
        }
    }

    for (int ki = 0; ki < nk; ki++) {
        __syncthreads();
        if (DBUF) {
            if (ki + 1 < nk) {
                int k0 = (ki + 1) << 6, nb = (ki + 1) & 1;
#pragma unroll
                for (int c = 0; c < 4; c++) {
                    int cid = wave * 4 + c;
                    GLD16(Ab + (size_t)(c * 8) * lda + k0, &sA[nb * 8192 + cid * 512]);
                    GLD16(Bb + (size_t)(c * 8) * ldb + k0, &sB[nb * 8192 + cid * 512]);
                }
            }
        } else {
            int k0 = ki << 6;
#pragma unroll
            for (int c = 0; c < 4; c++) {
                int cid = wave * 4 + c;
                GLD16(Ab + (size_t)(c * 8) * lda + k0, &sA[cid * 512]);
                GLD16(Bb + (size_t)(c * 8) * ldb + k0, &sB[cid * 512]);
            }
            __syncthreads();
        }
        const short* cA = &sA[DBUF ? (ki & 1) * 8192 : 0];
        const short* cB = &sB[DBUF ? (ki & 1) * 8192 : 0];
#pragma unroll
        for (int ko = 0; ko < 2; ko++) {
            bf16x8 af[4], bfr[4];
#pragma unroll
            for (int mt = 0; mt < 4; mt++) {
                int row = wm + mt * 16 + l15;
                af[mt] = *(const bf16x8*)&cA[(row * 8 + ((ko * 4 + quad) ^ sw)) * 8];
            }
#pragma unroll
            for (int nt = 0; nt < 4; nt++) {
                int row = wn + nt * 16 + l15;
                bfr[nt] = *(const bf16x8*)&cB[(row * 8 + ((ko * 4 + quad) ^ sw)) * 8];
            }
#pragma unroll
            for (int mt = 0; mt < 4; mt++)
#pragma unroll
                for (int nt = 0; nt < 4; nt++)
                    acc[mt][nt] = MFMA16(af[mt], bfr[nt], acc[mt][nt]);
        }
    }

#pragma unroll
    for (int mt = 0; mt < 4; mt++)
#pragma unroll
        for (int nt = 0; nt < 4; nt++) {
            int row0 = bm + wm + mt * 16 + quad * 4;
            int col  = bn + wn + nt * 16 + l15;
            if (qkv) {
                int seg = col >> 10, cloc = col & 1023;
                const float* bp = (seg == 0) ? bias : (seg == 1) ? bias2 : bias3;
                float bval = bp[cloc];
                if (seg == 2) {
                    int bb = row0 >> 10, l0 = row0 & 1023;
                    size_t page = (size_t)(bb * N_HEAD + (cloc >> 6)) * HEAD_D + (cloc & 63);
                    short4v pk = { f2bf(acc[mt][nt][0] + bval), f2bf(acc[mt][nt][1] + bval),
                                   f2bf(acc[mt][nt][2] + bval), f2bf(acc[mt][nt][3] + bval) };
                    *(short4v*)&Cvt[page * SEQ_L + l0] = pk;
                } else {
                    short* dst = Cb + (size_t)seg * ((size_t)N_TOK * D_MODEL);
#pragma unroll
                    for (int r = 0; r < 4; r++)
                        dst[(size_t)(row0 + r) * D_MODEL + cloc] = f2bf(acc[mt][nt][r] + bval);
                }
            } else {
#pragma unroll
                for (int r = 0; r < 4; r++) {
                    int row = row0 + r;
                    float v = acc[mt][nt][r] + bias[col];
                    if (act) v = v / (1.f + __expf(-1.702f * v));   // quick_gelu
                    if (resid) v += resid[(size_t)row * ldc + col];
                    if (Cb) Cb[(size_t)row * ldc + col] = f2bf(v);
                    else    Cf[(size_t)row * ldc + col] = v;
                }
            }
        }
}

// ---------------------------------------------------------------------------
// 256x256 (NREP=4) / 256x128 (NREP=2) 8-phase GEMM v3. Key properties:
//  * SINGLE barrier per phase: {reads; stage; [vmcnt]; BAR; lgkm0; MFMA} —
//    next phase's ds_reads issue while MFMAs drain (the overlap v2 lacked).
//  * Wave mapping restrided so each phase reads ONE contiguous half:
//    A-frag row = (mt>>2)*128 + (mt&3)*32 + (wave>>2)*16 + l15
//    B-frag row = nt*64 + (wave&3)*16 + l15
//    -> ph1 reads A rows 0-127 & B rows 0-127(NREP4: nt0,1), ph2 B hi,
//       ph3 A hi. Write-after-read gap >= 2 phases everywhere.
//  * Stage schedule (tiles t[buf0], t+1[buf1] this iter):
//      ph1: buf1.A0<-t+1   ph2: buf1.A1<-t+1   ph3: buf0.B0<-t+2
//      ph4: buf0.B1<-t+2   ph5: buf0.A0<-t+2   ph6: buf0.A1<-t+2
//      ph7: buf1.B0<-t+3   ph8: buf1.B1<-t+3
//    vmcnt(4/2) before BAR at ph4 (buf1 complete for ph5 reads) and
//    ph8 (buf0 complete for next ph1 reads). Never 0 in the loop.
//  * Fragment regs ping-pong [2] by buffer so ph4-MFMA / ph5-reads WAR
//    uses disjoint registers.
// ---------------------------------------------------------------------------
#define BAR() __builtin_amdgcn_s_barrier()
#define WAIT_LGKM0() do { asm volatile("s_waitcnt lgkmcnt(0)");               \
                          __builtin_amdgcn_sched_barrier(0); } while (0)

#define STA(buf, h, tt) do {                                                  \
    const short* s_ = Asrc + (size_t)((h) * 128) * lda + (size_t)(tt) * 64;   \
    GLD16(s_,                    &sAs[(buf)*16384 + (h)*8192        + wave*512]); \
    GLD16(s_ + (size_t)64 * lda, &sAs[(buf)*16384 + (h)*8192 + 4096 + wave*512]); \
} while (0)

#define STB(buf, h, tt) do {                                                  \
    if constexpr (NREP == 4) {                                                \
        const short* s_ = Bsrc + (size_t)((h) * 128) * ldb + (size_t)(tt) * 64; \
        GLD16(s_,                    &sBs[(buf)*16384 + (h)*8192        + wave*512]); \
        GLD16(s_ + (size_t)64 * ldb, &sBs[(buf)*16384 + (h)*8192 + 4096 + wave*512]); \
    } else {                                                                  \
        const short* s_ = Bsrc + (size_t)((h) * 64) * ldb + (size_t)(tt) * 64; \
        GLD16(s_, &sBs[(buf)*8192 + (h)*4096 + wave*512]);                    \
    }                                                                         \
} while (0)

#define VMCNT() do {                                                          \
    if constexpr (NREP == 4) asm volatile("s_waitcnt vmcnt(4)");              \
    else                     asm volatile("s_waitcnt vmcnt(2)");              \
} while (0)

// asm LDS reads: byte addr = base + buf*bytes + row*128 + swizzled chunk
#define RDB(buf, nt) do {                                                     \
    unsigned r_ = bBase + (buf) * BBUF                                        \
                + ((unsigned)((nt) * 64 + wni + l15) << 7);                   \
    bfr[buf][nt][0] = dsr(r_ + c0); bfr[buf][nt][1] = dsr(r_ + c1);           \
} while (0)
#define RDA(buf, mt8) do {                                                    \
    unsigned r_ = aBase + (buf) * 32768u                                      \
                + ((unsigned)((((mt8) >> 2) * 128) + (((mt8) & 3) * 32)       \
                              + wmi + l15) << 7);                             \
    afr[buf][(mt8) & 3][0] = dsr(r_ + c0);                                    \
    afr[buf][(mt8) & 3][1] = dsr(r_ + c1);                                    \
} while (0)

#define PH_MFMA(set, mh, nh)                                                  \
    __builtin_amdgcn_s_setprio(1);                                            \
    _Pragma("unroll")                                                         \
    for (int mt = 0; mt < 4; mt++)                                            \
        _Pragma("unroll")                                                     \
        for (int nt = 0; nt < NREP / 2; nt++) {                               \
            acc[(mh)*4 + mt][(nh)*(NREP/2) + nt] =                            \
                MFMA16(afr[set][mt][0], bfr[set][(nh)*(NREP/2) + nt][0],      \
                       acc[(mh)*4 + mt][(nh)*(NREP/2) + nt]);                 \
            acc[(mh)*4 + mt][(nh)*(NREP/2) + nt] =                            \
                MFMA16(afr[set][mt][1], bfr[set][(nh)*(NREP/2) + nt][1],      \
                       acc[(mh)*4 + mt][(nh)*(NREP/2) + nt]);                 \
        }                                                                     \
    __builtin_amdgcn_s_setprio(0);

template<int NREP>   // NREP=4 -> BN=256, NREP=2 -> BN=128
__global__ __launch_bounds__(512, 2) void gemm256(
    const short* __restrict__ A, int lda,
    const short* __restrict__ Bt, int ldb,
    const float* __restrict__ bias,
    const float* __restrict__ bias2,
    const float* __restrict__ bias3,
    const float* __restrict__ resid,
    float* __restrict__ Cf, short* __restrict__ Cb, short* __restrict__ Cvt,
    int ldc, int K, int act, int qkv, int gx)
{
    constexpr int BN = NREP * 64;
    constexpr unsigned BBUF = (unsigned)BN * 64u * 2u;   // B bytes/buf
    __shared__ __align__(16) short sAs[2 * 256 * 64];    // 64 KB, dbuf
    __shared__ __align__(16) short sBs[2 * BN  * 64];    // 64/32 KB, dbuf

    const int tid  = threadIdx.x;
    const int wave = tid >> 6, lane = tid & 63;
    const int quad = lane >> 4, l15 = lane & 15;
    const int wmi = (wave >> 2) * 16;    // A interleave base (row dim)
    const int wni = (wave & 3) * 16;     // B interleave base (col dim)
    const int sw = l15 & 7;

    const unsigned aBase = ldsoff(sAs);
    const unsigned bBase = ldsoff(sBs);
    const unsigned c0 = (unsigned)((quad ^ sw) << 4);
    const unsigned c1 = c0 ^ 64u;

    // XCD row-panel swizzle
    const int id = blockIdx.x;
    const int xcd = id & 7, j = id >> 3;
    const int bx = j % gx, by = xcd + 8 * (j / gx);
    const int bm = by * 256, bn = bx * BN;

    // staging: thread covers (row = tid>>3, chunk = (tid&7)^(row&7)) of a
    // 64-row half-stage; source pre-swizzled so linear LDS dest == swizzled.
    const int r_in = tid >> 3;
    const int csrc = (tid & 7) ^ (r_in & 7);
    const short* Asrc = A  + (size_t)(bm + r_in) * lda + csrc * 8;
    const short* Bsrc = Bt + (size_t)(bn + r_in) * ldb + csrc * 8;

    f32x4 acc[8][NREP];
#pragma unroll
    for (int i = 0; i < 8; i++)
#pragma unroll
        for (int jj = 0; jj < NREP; jj++) acc[i][jj] = (f32x4){0.f, 0.f, 0.f, 0.f};

    const int nk = K >> 6;

    // prologue: buf0 full (tile0) + buf1.B0,B1 (tile1); buf1.A staged by
    // the first iteration's ph1/ph2. vmcnt leaves buf1.B in flight.
    STB(0, 0, 0); STB(0, 1, 0);
    STA(0, 0, 0); STA(0, 1, 0);
    STB(1, 0, 1); STB(1, 1, 1);
    VMCNT();
    BAR();

    bf16x8 afr[2][4][2], bfr[2][NREP][2];

    for (int it = 0; it < nk; it += 2) {
        const int t1 = it + 1;                     // never wraps (nk even)
        int t2 = it + 2; if (t2 >= nk) t2 -= nk;   // wrapped dummy stages
        int t3 = it + 3; if (t3 >= nk) t3 -= nk;   // keep vmcnt counts uniform

        // ---- PH1: read buf0 {B-lo, A-lo}; stage buf1.A0 <- t1 ----
        RDB(0, 0);
        if constexpr (NREP == 4) RDB(0, 1);
        RDA(0, 0); RDA(0, 1); RDA(0, 2); RDA(0, 3);
        STA(1, 0, t1);
        BAR(); WAIT_LGKM0();
        PH_MFMA(0, 0, 0);
        // ---- PH2: read buf0 B-hi; stage buf1.A1 <- t1 ----
        if constexpr (NREP == 4) { RDB(0, 2); RDB(0, 3); }
        else                     { RDB(0, 1); }
        STA(1, 1, t1);
        BAR(); WAIT_LGKM0();
        PH_MFMA(0, 0, 1);
        // ---- PH3: read buf0 A-hi; stage buf0.B0 <- t2 ----
        RDA(0, 4); RDA(0, 5); RDA(0, 6); RDA(0, 7);
        STB(0, 0, t2);
        BAR(); WAIT_LGKM0();
        PH_MFMA(0, 1, 1);
        // ---- PH4: stage buf0.B1 <- t2; counted vmcnt (buf1 ready) ----
        STB(0, 1, t2);
        VMCNT();
        BAR();
        PH_MFMA(0, 1, 0);
        // ---- PH5: read buf1 {B-lo, A-lo}; stage buf0.A0 <- t2 ----
        RDB(1, 0);
        if constexpr (NREP == 4) RDB(1, 1);
        RDA(1, 0); RDA(1, 1); RDA(1, 2); RDA(1, 3);
        STA(0, 0, t2);
        BAR(); WAIT_LGKM0();
        PH_MFMA(1, 0, 0);
        // ---- PH6: read buf1 B-hi; stage buf0.A1 <- t2 ----
        if constexpr (NREP == 4) { RDB(1, 2); RDB(1, 3); }
        else                     { RDB(1, 1); }
        STA(0, 1, t2);
        BAR(); WAIT_LGKM0();
        PH_MFMA(1, 0, 1);
        // ---- PH7: read buf1 A-hi; stage buf1.B0 <- t3 ----
        RDA(1, 4); RDA(1, 5); RDA(1, 6); RDA(1, 7);
        STB(1, 0, t3);
        BAR(); WAIT_LGKM0();
        PH_MFMA(1, 1, 1);
        // ---- PH8: stage buf1.B1 <- t3; counted vmcnt (buf0 ready) ----
        STB(1, 1, t3);
        VMCNT();
        BAR();
        PH_MFMA(1, 1, 0);
    }

    // epilogue — interleaved mapping:
    // row0 = bm + (mt>>2)*128 + (mt&3)*32 + wmi + quad*4
    // col  = bn + nt*64 + wni + l15
#pragma unroll
    for (int mt = 0; mt < 8; mt++)
#pragma unroll
        for (int nt = 0; nt < NREP; nt++) {
            int row0 = bm + (mt >> 2) * 128 + (mt & 3) * 32 + wmi + quad * 4;
            int col  = bn + nt * 64 + wni + l15;
            if (qkv) {
                int seg = col >> 10, cloc = col & 1023;
                const float* bp = (seg == 0) ? bias : (seg == 1) ? bias2 : bias3;
                float bval = bp[cloc];
                if (seg == 2) {
                    int bb = row0 >> 10, l0 = row0 & 1023;
                    size_t page = (size_t)(bb * N_HEAD + (cloc >> 6)) * HEAD_D + (cloc & 63);
                    short4v pk = { f2bf(acc[mt][nt][0] + bval), f2bf(acc[mt][nt][1] + bval),
                                   f2bf(acc[mt][nt][2] + bval), f2bf(acc[mt][nt][3] + bval) };
                    *(short4v*)&Cvt[page * SEQ_L + l0] = pk;
                } else {
                    short* dst = Cb + (size_t)seg * ((size_t)N_TOK * D_MODEL);
#pragma unroll
                    for (int r = 0; r < 4; r++)
                        dst[(size_t)(row0 + r) * D_MODEL + cloc] = f2bf(acc[mt][nt][r] + bval);
                }
            } else {
#pragma unroll
                for (int r = 0; r < 4; r++) {
                    int row = row0 + r;
                    float v = acc[mt][nt][r] + bias[col];
                    if (act) v = v / (1.f + __expf(-1.702f * v));   // quick_gelu
                    if (resid) v += resid[(size_t)row * ldc + col];
                    if (Cb) Cb[(size_t)row * ldc + col] = f2bf(v);
                    else    Cf[(size_t)row * ldc + col] = v;
                }
            }
        }
}

// ---------------------------------------------------------------------------
// Flash attention, 128 q-rows/block (unchanged).
// ---------------------------------------------------------------------------
__global__ __launch_bounds__(256) void attn_kernel(
    const short* __restrict__ Q, const short* __restrict__ Kb,
    const short* __restrict__ Vt, const float* __restrict__ fmask,
    short* __restrict__ O)
{
    __shared__ __align__(16) short sK[8192];        // 16KB: slot=kc*128+key
    __shared__ __align__(16) short sV[8192];        // 16KB: slot=kc2*64+d
    __shared__ __align__(16) short sP[4][32 * 136]; // per-wave [32 q][136]
    __shared__ __align__(16) float sAl[4][2][20];

    const int g = blockIdx.x;
    const int xcd = g & 7, slot = g >> 3;
    const int qt = slot & 7, bhl = slot >> 3;
    const int bh = xcd * 16 + bhl;
    const int b = bh >> 4, h = bh & 15;

    const int tid = threadIdx.x;
    const int wave = tid >> 6, lane = tid & 63;
    const int quad = lane >> 4, l15 = lane & 15;

    const int qbase = b * SEQ_L + qt * 128;
    bf16x8 qf[2][2];
#pragma unroll
    for (int qh = 0; qh < 2; qh++) {
        const short* qp = Q + (size_t)(qbase + wave * 32 + qh * 16 + l15) * D_MODEL
                        + h * HEAD_D + quad * 8;
        qf[qh][0] = *(const bf16x8*)qp;
        qf[qh][1] = *(const bf16x8*)(qp + 32);
    }

    const short* Kbh = Kb + (size_t)b * SEQ_L * D_MODEL + h * HEAD_D;
    const short* Vbh = Vt + (size_t)(b * N_HEAD + h) * HEAD_D * SEQ_L;
    const float* mk  = fmask + b * SEQ_L;

    f32x4 o4[2][4];
#pragma unroll
    for (int qh = 0; qh < 2; qh++)
#pragma unroll
        for (int nt = 0; nt < 4; nt++) o4[qh][nt] = (f32x4){0.f, 0.f, 0.f, 0.f};
    float mrow[2] = {-1e30f, -1e30f}, lrow[2] = {0.f, 0.f};
    short* pslab = &sP[wave][0];         // per-wave private [32 q][136]
    const float CSC = 0.125f * 1.4426950408889634f;   // scale * log2(e)

    for (int kt = 0; kt < SEQ_L / 128; kt++) {
        __syncthreads();   // previous iter's frag reads done
#pragma unroll
        for (int j = 0; j < 4; j++) {
            int cid = wave * 4 + j;
            int kc = cid >> 1, key0 = (cid & 1) << 6;
            GLD16(Kbh + (size_t)(kt * 128 + key0 + lane) * D_MODEL + kc * 8,
                  &sK[cid * 512]);
            GLD16(Vbh + (size_t)lane * SEQ_L + kt * 128 + cid * 8,
                  &sV[cid * 512]);
        }
        __syncthreads();   // staging complete (vmcnt drained by barrier)

        f32x4 mkv[8];
#pragma unroll
        for (int sub = 0; sub < 8; sub++)
            mkv[sub] = *(const f32x4*)&mk[kt * 128 + sub * 16 + quad * 4];

        f32x4 s[8][2];
#pragma unroll
        for (int sub = 0; sub < 8; sub++) {
            bf16x8 kf0 = *(const bf16x8*)&sK[(quad * 128 + sub * 16 + l15) * 8];
            bf16x8 kf1 = *(const bf16x8*)&sK[((quad + 4) * 128 + sub * 16 + l15) * 8];
#pragma unroll
            for (int qh = 0; qh < 2; qh++) {
                s[sub][qh] = (f32x4){0.f, 0.f, 0.f, 0.f};
                s[sub][qh] = MFMA16(kf0, qf[qh][0], s[sub][qh]);
                s[sub][qh] = MFMA16(kf1, qf[qh][1], s[sub][qh]);
            }
        }
        float alpha[2];
#pragma unroll
        for (int qh = 0; qh < 2; qh++) {
#pragma unroll
            for (int sub = 0; sub < 8; sub++)
#pragma unroll
                for (int r = 0; r < 4; r++)
                    s[sub][qh][r] = s[sub][qh][r] * CSC + mkv[sub][r];
            f32x4 mx4 = s[0][qh];
#pragma unroll
            for (int sub = 1; sub < 8; sub++)
#pragma unroll
                for (int r = 0; r < 4; r++) mx4[r] = fmaxf(mx4[r], s[sub][qh][r]);
            float pmax = fmaxf(fmaxf(mx4[0], mx4[1]), fmaxf(mx4[2], mx4[3]));
            pmax = fmaxf(pmax, __shfl_xor(pmax, 16));
            pmax = fmaxf(pmax, __shfl_xor(pmax, 32));
            float mnew = fmaxf(mrow[qh], pmax);
            alpha[qh] = EXP2F(mrow[qh] - mnew);
            mrow[qh] = mnew;
            if (quad == 0) sAl[wave][qh][l15] = alpha[qh];

            float ls = 0.f;
#pragma unroll
            for (int sub = 0; sub < 8; sub++) {
                float p0 = EXP2F(s[sub][qh][0] - mnew);
                float p1 = EXP2F(s[sub][qh][1] - mnew);
                float p2 = EXP2F(s[sub][qh][2] - mnew);
                float p3 = EXP2F(s[sub][qh][3] - mnew);
                ls += (p0 + p1) + (p2 + p3);
                int2v pk = { pack2bf(p0, p1), pack2bf(p2, p3) };
                *(int2v*)&pslab[(qh * 16 + l15) * 136 + sub * 16 + quad * 4] = pk;
            }
            ls += __shfl_xor(ls, 16);
            ls += __shfl_xor(ls, 32);
            lrow[qh] = lrow[qh] * alpha[qh] + ls;
        }

#pragma unroll
        for (int qh = 0; qh < 2; qh++) {
            f32x4 av = *(const f32x4*)&sAl[wave][qh][quad * 4];
#pragma unroll
            for (int nt = 0; nt < 4; nt++)
#pragma unroll
                for (int r = 0; r < 4; r++) o4[qh][nt][r] *= av[r];
        }

        bf16x8 pf[2][4];
#pragma unroll
        for (int qh = 0; qh < 2; qh++)
#pragma unroll
            for (int c = 0; c < 4; c++)
                pf[qh][c] = *(const bf16x8*)&pslab[(qh * 16 + l15) * 136 + c * 32 + quad * 8];
#pragma unroll
        for (int nt = 0; nt < 4; nt++)
#pragma unroll
            for (int c = 0; c < 4; c++) {
                bf16x8 vfr = *(const bf16x8*)&sV[((c * 4 + quad) * 64 + nt * 16 + l15) * 8];
                o4[0][nt] = MFMA16(pf[0][c], vfr, o4[0][nt]);
                o4[1][nt] = MFMA16(pf[1][c], vfr, o4[1][nt]);
            }
    }
    if (quad == 0) {
        sAl[wave][0][l15] = 1.f / lrow[0];
        sAl[wave][1][l15] = 1.f / lrow[1];
    }
    __syncthreads();
#pragma unroll
    for (int qh = 0; qh < 2; qh++) {
        f32x4 iv = *(const f32x4*)&sAl[wave][qh][quad * 4];
#pragma unroll
        for (int nt = 0; nt < 4; nt++)
#pragma unroll
            for (int r = 0; r < 4; r++)
                O[(size_t)(qbase + wave * 32 + qh * 16 + quad * 4 + r) * D_MODEL
                  + h * HEAD_D + nt * 16 + l15] = f2bf(o4[qh][nt][r] * iv[r]);
    }
}

// ---------------------------------------------------------------------------
// Launch
// ---------------------------------------------------------------------------
extern "C" void kernel_launch(void* const* d_in, const int* in_sizes, int n_in,
                              void* d_out, int out_size, void* d_ws, size_t ws_size,
                              hipStream_t stream)
{
    const float* x     = (const float*)d_in[0];
    const int*   amask = (const int*)  d_in[1];
    const float* wq    = (const float*)d_in[2];
    const float* bq    = (const float*)d_in[3];
    const float* wk    = (const float*)d_in[4];
    const float* bk    = (const float*)d_in[5];
    const float* wv    = (const float*)d_in[6];
    const float* bv    = (const float*)d_in[7];
    const float* wo    = (const float*)d_in[8];
    const float* bo    = (const float*)d_in[9];
    const float* ln1s  = (const float*)d_in[10];
    const float* ln1b  = (const float*)d_in[11];
    const float* ln2s  = (const float*)d_in[12];
    const float* ln2b  = (const float*)d_in[13];
    const float* w1    = (const float*)d_in[14];
    const float* b1    = (const float*)d_in[15];
    const float* w2    = (const float*)d_in[16];
    const float* b2    = (const float*)d_in[17];
    float* out = (float*)d_out;

    char* w = (char*)d_ws;
    short* wqkvt = (short*)(w + (size_t)0);          // [3072][1024] bf16, 6MB
    short* wot   = (short*)(w + ((size_t)6  << 20));
    short* w1t   = (short*)(w + ((size_t)8  << 20));
    short* w2t   = (short*)(w + ((size_t)16 << 20));
    short* hb    = (short*)(w + ((size_t)24 << 20)); // LN1 out, later LN2 out
    short* qb    = (short*)(w + ((size_t)40 << 20)); // qb,kbf contiguous:
    short* kbf   = (short*)(w + ((size_t)56 << 20)); //   16MB stride for qkv mode
    short* attnb = (short*)(w + ((size_t)72 << 20));
    short* vtb   = (short*)(w + ((size_t)88 << 20));
    short* ffb   = qb;   // q/k/vt dead by MLP1 (64 MB span 40..104)
    float* fmaskb = (float*)d_out;

    dim3 blk(256), blk512(512);

    prep_kernel<<<dim3(12320), blk, 0, stream>>>(wq, wk, wv, wo, w1, w2, amask,
                                                 wqkvt, wot, w1t, w2t, fmaskb);

    // 1) h = LN1(x) -> bf16
    ln_kernel<<<N_TOK, blk, 0, stream>>>(x, ln1s, ln1b, hb);

    // 2) fused QKV GEMM: legacy 128^2 single-buffer (proven)
    gemm_bf16<0><<<dim3(24 * 64), blk, 0, stream>>>(
        hb, 1024, wqkvt, 1024, bq, bk, bv, nullptr,
        nullptr, qb, vtb, 1024, 1024, 0, 1, 24);

    // 3) flash attention -> attnb (bf16)
    attn_kernel<<<dim3(1024), blk, 0, stream>>>(qb, kbf, vtb, fmaskb, attnb);

    // 4) out = x + attn @ wo + bo  (legacy dbuf-128^2)
    gemm_bf16<1><<<dim3(8 * 64), blk, 0, stream>>>(
        attnb, 1024, wot, 1024, bo, nullptr, nullptr, x,
        out, nullptr, nullptr, 1024, 1024, 0, 0, 8);

    // 5) h = LN2(out) -> bf16
    ln_kernel<<<N_TOK, blk, 0, stream>>>(out, ln2s, ln2b, hb);

    // 6) MLP1: 256^2 8-phase v3, grid 512; MLP2: 256x128 v3, grid 256
    gemm256<4><<<dim3(512), blk512, 0, stream>>>(
        hb, 1024, w1t, 1024, b1, nullptr, nullptr, nullptr,
        nullptr, ffb, nullptr, 4096, 1024, 1, 0, 16);
    gemm256<2><<<dim3(256), blk512, 0, stream>>>(
        ffb, 4096, w2t, 4096, b2, nullptr, nullptr, out,
        out, nullptr, nullptr, 1024, 4096, 0, 0, 8);
}

// Round 4
// 550.840 us; speedup vs baseline: 1.3583x; 1.0724x over previous
//
#include <hip/hip_runtime.h>
#include <math.h>

#define D_MODEL 1024
#define N_TOK   8192
#define SEQ_L   1024
#define N_HEAD  16
#define HEAD_D  64
#define FF_DIM  4096

typedef __attribute__((ext_vector_type(8))) short bf16x8;   // 8 bf16 = 4 VGPRs
typedef __attribute__((ext_vector_type(4))) short short4v;
typedef __attribute__((ext_vector_type(2))) int  int2v;
typedef __attribute__((ext_vector_type(4))) float f32x4;

#define MFMA16(a, b, c) __builtin_amdgcn_mfma_f32_16x16x32_bf16((a), (b), (c), 0, 0, 0)

// async global->LDS, 16B per lane; LDS dest = wave-uniform base + lane*16
#define GLD16(gp, lp) __builtin_amdgcn_global_load_lds(                      \
    (const __attribute__((address_space(1))) void*)(gp),                     \
    (__attribute__((address_space(3))) void*)(lp), 16, 0, 0)

#if defined(__has_builtin)
#if __has_builtin(__builtin_amdgcn_exp2f)
#define EXP2F(x) __builtin_amdgcn_exp2f(x)
#else
#define EXP2F(x) exp2f(x)
#endif
#else
#define EXP2F(x) exp2f(x)
#endif

__device__ __forceinline__ short f2bf(float f) {   // fp32 -> bf16 (RNE)
    unsigned u = __float_as_uint(f);
    u += 0x7fffu + ((u >> 16) & 1u);
    return (short)(u >> 16);
}

// pack two fp32 -> two bf16 (round-nearest-up) in one v_perm
__device__ __forceinline__ int pack2bf(float a, float b) {
    unsigned ua = __float_as_uint(a) + 0x8000u;
    unsigned ub = __float_as_uint(b) + 0x8000u;
    return __builtin_amdgcn_perm(ub, ua, 0x07060302u);
}

// ---------------------------------------------------------------------------
// LayerNorm fp32 -> bf16. One block (256 thr) per token.
// ---------------------------------------------------------------------------
__global__ __launch_bounds__(256) void ln_kernel(const float* __restrict__ x,
                                                 const float* __restrict__ g,
                                                 const float* __restrict__ b,
                                                 short* __restrict__ o)
{
    int t = blockIdx.x;
    const float* xr = x + (size_t)t * D_MODEL;
    short* orow = o + (size_t)t * D_MODEL;
    float vals[4];
    float lsum = 0.f, lsq = 0.f;
#pragma unroll
    for (int i = 0; i < 4; i++) {
        float v = xr[threadIdx.x + i * 256];
        vals[i] = v; lsum += v; lsq += v * v;
    }
#pragma unroll
    for (int off = 32; off > 0; off >>= 1) {
        lsum += __shfl_down(lsum, off);
        lsq  += __shfl_down(lsq,  off);
    }
    __shared__ float red[8];
    int wid = threadIdx.x >> 6, lane = threadIdx.x & 63;
    if (lane == 0) { red[wid] = lsum; red[4 + wid] = lsq; }
    __syncthreads();
    if (threadIdx.x == 0) {
        red[0] = red[0] + red[1] + red[2] + red[3];
        red[4] = red[4] + red[5] + red[6] + red[7];
    }
    __syncthreads();
    float mean = red[0] * (1.f / D_MODEL);
    float var  = red[4] * (1.f / D_MODEL) - mean * mean;
    float inv  = rsqrtf(var + 1e-5f);
#pragma unroll
    for (int i = 0; i < 4; i++) {
        int c = threadIdx.x + i * 256;
        orow[c] = f2bf((vals[i] - mean) * inv * g[c] + b[c]);
    }
}

// ---------------------------------------------------------------------------
// Fused prep: six W [K,N] fp32 -> W^T [N,K] bf16 transposes + fp32 mask,
// all in ONE dispatch. Block id ranges select the job; 32x32 tiles.
// ---------------------------------------------------------------------------
__global__ __launch_bounds__(256) void prep_kernel(
    const float* __restrict__ wq, const float* __restrict__ wk,
    const float* __restrict__ wv, const float* __restrict__ wo,
    const float* __restrict__ w1, const float* __restrict__ w2,
    const int*   __restrict__ amask,
    short* __restrict__ wqkvt, short* __restrict__ wot,
    short* __restrict__ w1t,  short* __restrict__ w2t,
    float* __restrict__ fmask)
{
    int id = blockIdx.x;
    if (id >= 12288) {   // mask job: 32 blocks x 256 = 8192 entries
        int i = (id - 12288) * 256 + threadIdx.x;
        fmask[i] = (amask[i] > 0) ? 0.f : -1e30f;
        return;
    }
    const float* src; short* dst; int R, C, tloc, csh;
    if (id < 4096) {
        int wsel = id >> 10; tloc = id & 1023; R = 1024; C = 1024; csh = 5;
        src = (wsel == 0) ? wq : (wsel == 1) ? wk : (wsel == 2) ? wv : wo;
        dst = (wsel == 3) ? wot : (wqkvt + (size_t)wsel * 1024 * 1024);
    } else if (id < 8192) {
        tloc = id - 4096; R = 1024; C = 4096; csh = 7; src = w1; dst = w1t;
    } else {
        tloc = id - 8192; R = 4096; C = 1024; csh = 5; src = w2; dst = w2t;
    }
    int ty = tloc >> csh, tx = tloc & ((1 << csh) - 1);
    int r0 = ty * 32, c0 = tx * 32;
    __shared__ float t[32][33];
    int tid = threadIdx.x;
#pragma unroll
    for (int i = 0; i < 4; i++) {
        int idx = i * 256 + tid;
        int r = idx >> 5, c = idx & 31;
        t[r][c] = src[(size_t)(r0 + r) * C + c0 + c];
    }
    __syncthreads();
#pragma unroll
    for (int i = 0; i < 4; i++) {
        int idx = i * 256 + tid;
        int rr = idx >> 5, cc = idx & 31;
        dst[(size_t)(c0 + rr) * R + r0 + cc] = f2bf(t[cc][rr]);
    }
}

// ---------------------------------------------------------------------------
// bf16 MFMA GEMM, BK=64, XOR-swizzled LDS, buffering templated:
//   DBUF=0: single 32KB buffer — best when grid allows >2 blocks/CU.
//   DBUF=1: double 64KB buffer, prefetch k+1 before compute k — best for
//           512-block grids already capped at 2 blocks/CU.
// LDS slot(row, chunk) = row*8 + (chunk ^ (row&7))  [16B slots].
// Grid: 1-D, XCD row-panel swizzle: xcd=id&7 owns rows {xcd+8j}.
// C/D layout: col=lane&15, row=quad*4+reg.
// ---------------------------------------------------------------------------
template<int DBUF>
__global__ __launch_bounds__(256) void gemm_bf16(
    const short* __restrict__ A, int lda,
    const short* __restrict__ Bt, int ldb,
    const float* __restrict__ bias,
    const float* __restrict__ bias2,
    const float* __restrict__ bias3,
    const float* __restrict__ resid,
    float* __restrict__ Cf, short* __restrict__ Cb, short* __restrict__ Cvt,
    int ldc, int K, int act, int qkv, int gx)
{
    __shared__ __align__(16) short sA[(1 + DBUF) * 8192];   // swizzled
    __shared__ __align__(16) short sB[(1 + DBUF) * 8192];
    const int tid = threadIdx.x;
    const int lane = tid & 63, wave = tid >> 6;
    const int quad = lane >> 4, l15 = lane & 15;

    const int id = blockIdx.x;
    const int xcd = id & 7, j = id >> 3;
    const int bx = j % gx, by = xcd + 8 * (j / gx);
    const int bm = by * 128, bn = bx * 128;
    const int wm = (wave >> 1) * 64, wn = (wave & 1) * 64;

    const int lr = lane >> 3;            // 0..7 row within an 8-row call
    const int lc = (lane & 7) ^ lr;      // chunk ^ (row&7)
    const int sw = l15 & 7;              // read-side swizzle key

    const short* Ab = A  + (size_t)(bm + wave * 32 + lr) * lda + lc * 8;
    const short* Bb = Bt + (size_t)(bn + wave * 32 + lr) * ldb + lc * 8;

    f32x4 acc[4][4];
#pragma unroll
    for (int i = 0; i < 4; i++)
#pragma unroll
        for (int jj = 0; jj < 4; jj++) acc[i][jj] = (f32x4){0.f, 0.f, 0.f, 0.f};

    const int nk = K >> 6;

    if (DBUF) {
#pragma unroll
        for (int c = 0; c < 4; c++) {
            int cid = wave * 4 + c;
            GLD16(Ab + (size_t)(c * 8) * lda, &sA[cid * 512]);
            GLD16(Bb + (size_t)(c * 8) * ldb, &sB[cid * 512]);
        }
    }

    for (int ki = 0; ki < nk; ki++) {
        __syncthreads();
        if (DBUF) {
            if (ki + 1 < nk) {
                int k0 = (ki + 1) << 6, nb = (ki + 1) & 1;
#pragma unroll
                for (int c = 0; c < 4; c++) {
                    int cid = wave * 4 + c;
                    GLD16(Ab + (size_t)(c * 8) * lda + k0, &sA[nb * 8192 + cid * 512]);
                    GLD16(Bb + (size_t)(c * 8) * ldb + k0, &sB[nb * 8192 + cid * 512]);
                }
            }
        } else {
            int k0 = ki << 6;
#pragma unroll
            for (int c = 0; c < 4; c++) {
                int cid = wave * 4 + c;
                GLD16(Ab + (size_t)(c * 8) * lda + k0, &sA[cid * 512]);
                GLD16(Bb + (size_t)(c * 8) * ldb + k0, &sB[cid * 512]);
            }
            __syncthreads();
        }
        const short* cA = &sA[DBUF ? (ki & 1) * 8192 : 0];
        const short* cB = &sB[DBUF ? (ki & 1) * 8192 : 0];
#pragma unroll
        for (int ko = 0; ko < 2; ko++) {
            bf16x8 af[4], bfr[4];
#pragma unroll
            for (int mt = 0; mt < 4; mt++) {
                int row = wm + mt * 16 + l15;
                af[mt] = *(const bf16x8*)&cA[(row * 8 + ((ko * 4 + quad) ^ sw)) * 8];
            }
#pragma unroll
            for (int nt = 0; nt < 4; nt++) {
                int row = wn + nt * 16 + l15;
                bfr[nt] = *(const bf16x8*)&cB[(row * 8 + ((ko * 4 + quad) ^ sw)) * 8];
            }
#pragma unroll
            for (int mt = 0; mt < 4; mt++)
#pragma unroll
                for (int nt = 0; nt < 4; nt++)
                    acc[mt][nt] = MFMA16(af[mt], bfr[nt], acc[mt][nt]);
        }
    }

#pragma unroll
    for (int mt = 0; mt < 4; mt++)
#pragma unroll
        for (int nt = 0; nt < 4; nt++) {
            int row0 = bm + wm + mt * 16 + quad * 4;
            int col  = bn + wn + nt * 16 + l15;
            if (qkv) {
                int seg = col >> 10, cloc = col & 1023;
                const float* bp = (seg == 0) ? bias : (seg == 1) ? bias2 : bias3;
                float bval = bp[cloc];
                if (seg == 2) {
                    // V transposed store: page=(b*H+h)*64+d, index = seq pos
                    int bb = row0 >> 10, l0 = row0 & 1023;
                    size_t page = (size_t)(bb * N_HEAD + (cloc >> 6)) * HEAD_D + (cloc & 63);
                    short4v pk = { f2bf(acc[mt][nt][0] + bval), f2bf(acc[mt][nt][1] + bval),
                                   f2bf(acc[mt][nt][2] + bval), f2bf(acc[mt][nt][3] + bval) };
                    *(short4v*)&Cvt[page * SEQ_L + l0] = pk;
                } else {
                    short* dst = Cb + (size_t)seg * ((size_t)N_TOK * D_MODEL);
#pragma unroll
                    for (int r = 0; r < 4; r++)
                        dst[(size_t)(row0 + r) * D_MODEL + cloc] = f2bf(acc[mt][nt][r] + bval);
                }
            } else {
#pragma unroll
                for (int r = 0; r < 4; r++) {
                    int row = row0 + r;
                    float v = acc[mt][nt][r] + bias[col];
                    if (act) v = v / (1.f + __expf(-1.702f * v));   // quick_gelu
                    if (resid) v += resid[(size_t)row * ldc + col];
                    if (Cb) Cb[(size_t)row * ldc + col] = f2bf(v);
                    else    Cf[(size_t)row * ldc + col] = v;
                }
            }
        }
}

// ---------------------------------------------------------------------------
// Flash attention, 128 q-rows/block. Round-4 change: V is NOT LDS-staged —
// V^T is L2-resident per (b,h) (128 KB, all 8 q-tile blocks of a bh pinned
// to one XCD by the grid swizzle), so PV B-frags are direct global loads
// (m169: V-staging at S=1024 is pure overhead). LDS 67->51 KB => 3 blocks/CU.
// ---------------------------------------------------------------------------
__global__ __launch_bounds__(256) void attn_kernel(
    const short* __restrict__ Q, const short* __restrict__ Kb,
    const short* __restrict__ Vt, const float* __restrict__ fmask,
    short* __restrict__ O)
{
    __shared__ __align__(16) short sK[8192];        // 16KB: slot=kc*128+key
    __shared__ __align__(16) short sP[4][32 * 136]; // per-wave [32 q][136]
    __shared__ __align__(16) float sAl[4][2][20];

    const int g = blockIdx.x;
    const int xcd = g & 7, slot = g >> 3;
    const int qt = slot & 7, bhl = slot >> 3;
    const int bh = xcd * 16 + bhl;
    const int b = bh >> 4, h = bh & 15;

    const int tid = threadIdx.x;
    const int wave = tid >> 6, lane = tid & 63;
    const int quad = lane >> 4, l15 = lane & 15;

    const int qbase = b * SEQ_L + qt * 128;
    bf16x8 qf[2][2];
#pragma unroll
    for (int qh = 0; qh < 2; qh++) {
        const short* qp = Q + (size_t)(qbase + wave * 32 + qh * 16 + l15) * D_MODEL
                        + h * HEAD_D + quad * 8;
        qf[qh][0] = *(const bf16x8*)qp;
        qf[qh][1] = *(const bf16x8*)(qp + 32);
    }

    const short* Kbh = Kb + (size_t)b * SEQ_L * D_MODEL + h * HEAD_D;
    const short* Vbh = Vt + (size_t)(b * N_HEAD + h) * HEAD_D * SEQ_L;
    const float* mk  = fmask + b * SEQ_L;

    f32x4 o4[2][4];
#pragma unroll
    for (int qh = 0; qh < 2; qh++)
#pragma unroll
        for (int nt = 0; nt < 4; nt++) o4[qh][nt] = (f32x4){0.f, 0.f, 0.f, 0.f};
    float mrow[2] = {-1e30f, -1e30f}, lrow[2] = {0.f, 0.f};
    short* pslab = &sP[wave][0];         // per-wave private [32 q][136]
    const float CSC = 0.125f * 1.4426950408889634f;   // scale * log2(e)

    for (int kt = 0; kt < SEQ_L / 128; kt++) {
        __syncthreads();   // previous iter's sK frag reads done
        // ---- stage K-tile only (4 GLD16 per wave) ----
#pragma unroll
        for (int jj = 0; jj < 4; jj++) {
            int cid = wave * 4 + jj;
            int kc = cid >> 1, key0 = (cid & 1) << 6;
            GLD16(Kbh + (size_t)(kt * 128 + key0 + lane) * D_MODEL + kc * 8,
                  &sK[cid * 512]);
        }
        __syncthreads();   // staging complete (vmcnt drained by barrier)

        // ---- mask loads (f32x4, indexed by key=row) ----
        f32x4 mkv[8];
#pragma unroll
        for (int sub = 0; sub < 8; sub++)
            mkv[sub] = *(const f32x4*)&mk[kt * 128 + sub * 16 + quad * 4];

        // ---- S^T = K·Q^T for both q-halves (K frags reused) ----
        f32x4 s[8][2];
#pragma unroll
        for (int sub = 0; sub < 8; sub++) {
            bf16x8 kf0 = *(const bf16x8*)&sK[(quad * 128 + sub * 16 + l15) * 8];
            bf16x8 kf1 = *(const bf16x8*)&sK[((quad + 4) * 128 + sub * 16 + l15) * 8];
#pragma unroll
            for (int qh = 0; qh < 2; qh++) {
                s[sub][qh] = (f32x4){0.f, 0.f, 0.f, 0.f};
                s[sub][qh] = MFMA16(kf0, qf[qh][0], s[sub][qh]);
                s[sub][qh] = MFMA16(kf1, qf[qh][1], s[sub][qh]);
            }
        }
        // ---- scale+mask, max, exp2, pack, l-sum — two independent chains ----
        float alpha[2];
#pragma unroll
        for (int qh = 0; qh < 2; qh++) {
#pragma unroll
            for (int sub = 0; sub < 8; sub++)
#pragma unroll
                for (int r = 0; r < 4; r++)
                    s[sub][qh][r] = s[sub][qh][r] * CSC + mkv[sub][r];
            f32x4 mx4 = s[0][qh];
#pragma unroll
            for (int sub = 1; sub < 8; sub++)
#pragma unroll
                for (int r = 0; r < 4; r++) mx4[r] = fmaxf(mx4[r], s[sub][qh][r]);
            float pmax = fmaxf(fmaxf(mx4[0], mx4[1]), fmaxf(mx4[2], mx4[3]));
            pmax = fmaxf(pmax, __shfl_xor(pmax, 16));
            pmax = fmaxf(pmax, __shfl_xor(pmax, 32));
            float mnew = fmaxf(mrow[qh], pmax);
            alpha[qh] = EXP2F(mrow[qh] - mnew);
            mrow[qh] = mnew;
            if (quad == 0) sAl[wave][qh][l15] = alpha[qh];

            float ls = 0.f;
#pragma unroll
            for (int sub = 0; sub < 8; sub++) {
                float p0 = EXP2F(s[sub][qh][0] - mnew);
                float p1 = EXP2F(s[sub][qh][1] - mnew);
                float p2 = EXP2F(s[sub][qh][2] - mnew);
                float p3 = EXP2F(s[sub][qh][3] - mnew);
                ls += (p0 + p1) + (p2 + p3);
                int2v pk = { pack2bf(p0, p1), pack2bf(p2, p3) };
                *(int2v*)&pslab[(qh * 16 + l15) * 136 + sub * 16 + quad * 4] = pk;
            }
            ls += __shfl_xor(ls, 16);
            ls += __shfl_xor(ls, 32);
            lrow[qh] = lrow[qh] * alpha[qh] + ls;
        }

        // ---- rescale O by alpha (per-row broadcast) ----
#pragma unroll
        for (int qh = 0; qh < 2; qh++) {
            f32x4 av = *(const f32x4*)&sAl[wave][qh][quad * 4];
#pragma unroll
            for (int nt = 0; nt < 4; nt++)
#pragma unroll
                for (int r = 0; r < 4; r++) o4[qh][nt][r] *= av[r];
        }

        // ---- PV: P A-frags from per-wave slab; V B-frags DIRECT from L2 ----
        bf16x8 pf[2][4];
#pragma unroll
        for (int qh = 0; qh < 2; qh++)
#pragma unroll
            for (int c = 0; c < 4; c++)
                pf[qh][c] = *(const bf16x8*)&pslab[(qh * 16 + l15) * 136 + c * 32 + quad * 8];
#pragma unroll
        for (int nt = 0; nt < 4; nt++) {
            bf16x8 vv[4];
#pragma unroll
            for (int c = 0; c < 4; c++)
                vv[c] = *(const bf16x8*)&Vbh[(size_t)(nt * 16 + l15) * SEQ_L
                                             + kt * 128 + (c * 4 + quad) * 8];
#pragma unroll
            for (int c = 0; c < 4; c++) {
                o4[0][nt] = MFMA16(pf[0][c], vv[c], o4[0][nt]);
                o4[1][nt] = MFMA16(pf[1][c], vv[c], o4[1][nt]);
            }
        }
    }
    // final 1/l broadcast to O rows
    if (quad == 0) {
        sAl[wave][0][l15] = 1.f / lrow[0];
        sAl[wave][1][l15] = 1.f / lrow[1];
    }
    __syncthreads();
#pragma unroll
    for (int qh = 0; qh < 2; qh++) {
        f32x4 iv = *(const f32x4*)&sAl[wave][qh][quad * 4];
#pragma unroll
        for (int nt = 0; nt < 4; nt++)
#pragma unroll
            for (int r = 0; r < 4; r++)
                O[(size_t)(qbase + wave * 32 + qh * 16 + quad * 4 + r) * D_MODEL
                  + h * HEAD_D + nt * 16 + l15] = f2bf(o4[qh][nt][r] * iv[r]);
    }
}

// ---------------------------------------------------------------------------
// Launch
// ---------------------------------------------------------------------------
extern "C" void kernel_launch(void* const* d_in, const int* in_sizes, int n_in,
                              void* d_out, int out_size, void* d_ws, size_t ws_size,
                              hipStream_t stream)
{
    const float* x     = (const float*)d_in[0];
    const int*   amask = (const int*)  d_in[1];
    const float* wq    = (const float*)d_in[2];
    const float* bq    = (const float*)d_in[3];
    const float* wk    = (const float*)d_in[4];
    const float* bk    = (const float*)d_in[5];
    const float* wv    = (const float*)d_in[6];
    const float* bv    = (const float*)d_in[7];
    const float* wo    = (const float*)d_in[8];
    const float* bo    = (const float*)d_in[9];
    const float* ln1s  = (const float*)d_in[10];
    const float* ln1b  = (const float*)d_in[11];
    const float* ln2s  = (const float*)d_in[12];
    const float* ln2b  = (const float*)d_in[13];
    const float* w1    = (const float*)d_in[14];
    const float* b1    = (const float*)d_in[15];
    const float* w2    = (const float*)d_in[16];
    const float* b2    = (const float*)d_in[17];
    float* out = (float*)d_out;

    // workspace layout (bytes; peak 104 MB, proven available)
    char* w = (char*)d_ws;
    short* wqkvt = (short*)(w + (size_t)0);          // [3072][1024] bf16, 6MB
    short* wot   = (short*)(w + ((size_t)6  << 20));
    short* w1t   = (short*)(w + ((size_t)8  << 20));
    short* w2t   = (short*)(w + ((size_t)16 << 20));
    short* hb    = (short*)(w + ((size_t)24 << 20)); // LN1 out, later LN2 out
    short* qb    = (short*)(w + ((size_t)40 << 20)); // qb,kbf contiguous:
    short* kbf   = (short*)(w + ((size_t)56 << 20)); //   16MB stride for qkv mode
    short* attnb = (short*)(w + ((size_t)72 << 20));
    short* vtb   = (short*)(w + ((size_t)88 << 20));
    short* ffb   = qb;   // q/k/vt dead by MLP1 (64 MB span 40..104)
    // fmask lives in d_out: free until the O-proj GEMM (step 4) overwrites
    // it, and attn (step 3) has finished reading it by then (same stream).
    float* fmaskb = (float*)d_out;

    dim3 blk(256);

    // prep: six transposes + mask in ONE dispatch
    prep_kernel<<<dim3(12320), blk, 0, stream>>>(wq, wk, wv, wo, w1, w2, amask,
                                                 wqkvt, wot, w1t, w2t, fmaskb);

    // 1) h = LN1(x) -> bf16
    ln_kernel<<<N_TOK, blk, 0, stream>>>(x, ln1s, ln1b, hb);

    // 2) fused QKV GEMM (gx=24, single-buffer: 1536 blocks want occupancy)
    gemm_bf16<0><<<dim3(24 * 64), blk, 0, stream>>>(
        hb, 1024, wqkvt, 1024, bq, bk, bv, nullptr,
        nullptr, qb, vtb, 1024, 1024, 0, 1, 24);

    // 3) flash attention -> attnb (bf16); 1024 blocks, 128 q-rows each
    attn_kernel<<<dim3(1024), blk, 0, stream>>>(qb, kbf, vtb, fmaskb, attnb);

    // 4) out = x + attn @ wo + bo  (512 blocks = 2/CU -> dbuf wins)
    gemm_bf16<1><<<dim3(8 * 64), blk, 0, stream>>>(
        attnb, 1024, wot, 1024, bo, nullptr, nullptr, x,
        out, nullptr, nullptr, 1024, 1024, 0, 0, 8);

    // 5) h = LN2(out) -> bf16
    ln_kernel<<<N_TOK, blk, 0, stream>>>(out, ln2s, ln2b, hb);

    // 6) MLP: MLP1 single-buffer (2048 blocks), MLP2 dbuf (512 blocks)
    gemm_bf16<0><<<dim3(32 * 64), blk, 0, stream>>>(
        hb, 1024, w1t, 1024, b1, nullptr, nullptr, nullptr,
        nullptr, ffb, nullptr, 4096, 1024, 1, 0, 32);
    gemm_bf16<1><<<dim3(8 * 64), blk, 0, stream>>>(
        ffb, 4096, w2t, 4096, b2, nullptr, nullptr, out,
        out, nullptr, nullptr, 1024, 4096, 0, 0, 8);
}